// Round 9
// baseline (101.905 us; speedup 1.0000x reference)
//
#include <hip/hip_runtime.h>
#include <hip/hip_bf16.h>
#include <math.h>

#define N_D 128
#define TEMP_INV 14.285714285714286f
#define EXP2_SCALE 20.60992915555662f   // (1/0.07) * log2(e)
#define SQRT_E2S 4.539816f              // sqrt(EXP2_SCALE); folded into bf16 data

using bf16x8 = __attribute__((ext_vector_type(8))) short;
using f32x4  = __attribute__((ext_vector_type(4))) float;

// ---------------- ws layout (bytes), N=8192 fast path ----------------
#define EBF_OFF   0u          // 8192*128 bf16, PRE-SWIZZLED rows, PRE-SCALED by SQRT_E2S (2 MB)
#define SE_OFF    2097152u    // 8192 f32 row exp-sums (zeroed by k_pre misc block)
#define S_OFF     2129920u    // 100*128 f32 class sums (raw emb)
#define CNT_OFF   2181120u    // 100 f32 class counts
#define CTR_OFF   2181632u    // 256 ints: [0]=flag64 [1]=FIN(f32) [2]=DONE [8+rg]=rowgroup ctr
#define WS_NEEDED 2182656u

__device__ __forceinline__ ushort f2bf(float f) {
    __hip_bfloat16 h = __float2bfloat16(f);
    return *reinterpret_cast<ushort*>(&h);
}

__device__ __forceinline__ float fast_exp2(float x) {
#if __has_builtin(__builtin_amdgcn_exp2f)
    return __builtin_amdgcn_exp2f(x);
#else
    float r; asm("v_exp_f32 %0, %1" : "=v"(r) : "v"(x)); return r;
#endif
}

__device__ int detect_i64(const int* lab, int N) {
    __shared__ int s_any;
    if (threadIdx.x == 0) s_any = 0;
    __syncthreads();
    int any = 0;
    for (int i = threadIdx.x; i < (N >> 1); i += blockDim.x)
        any |= (lab[2 * i + 1] != 0);
    if (__any(any) && (threadIdx.x & 63) == 0) atomicOr(&s_any, 1);
    __syncthreads();
    return s_any ? 0 : 1;   // all odd words zero => int64
}

// ====== k_pre: [0,512) bf16 convert (pre-swizzled, pre-scaled) | [512,612) class sums | 612 misc ======
__global__ __launch_bounds__(256) void k_pre(const float* __restrict__ emb,
                                             const int* __restrict__ lab,
                                             char* __restrict__ ws, int N) {
    __shared__ int list[2048];
    __shared__ int lcnt;
    __shared__ float tmp[128];
    const int blk = blockIdx.x;
    const int tid = threadIdx.x;

    if (blk < 512) {
        // convert: id -> row g, slot s; store orig[g][s ^ (g&15)] at [g][s], scaled
        int id = blk * 256 + tid;            // 0 .. 131071
        int g = id >> 4, s = id & 15;
        int srcslot = s ^ (g & 15);
        const float* src = emb + (size_t)g * N_D + srcslot * 8;
        float4 v0 = *(const float4*)src;
        float4 v1 = *(const float4*)(src + 4);
        uint4 o;
        o.x = (uint)f2bf(v0.x * SQRT_E2S) | ((uint)f2bf(v0.y * SQRT_E2S) << 16);
        o.y = (uint)f2bf(v0.z * SQRT_E2S) | ((uint)f2bf(v0.w * SQRT_E2S) << 16);
        o.z = (uint)f2bf(v1.x * SQRT_E2S) | ((uint)f2bf(v1.y * SQRT_E2S) << 16);
        o.w = (uint)f2bf(v1.z * SQRT_E2S) | ((uint)f2bf(v1.w * SQRT_E2S) << 16);
        ((uint4*)(ws + EBF_OFF))[id] = o;
        return;
    }
    if (blk < 612) {
        // class-sum for class c: chunked index-list gather + prefetched row sum (RAW values)
        int c = blk - 512;
        int flag64 = detect_i64(lab, N);
        int stream = tid >> 7;      // 0/1
        int d = tid & 127;
        float acc = 0.f;
        int total = 0;
        for (int base = 0; base < N; base += 2048) {
            if (tid == 0) lcnt = 0;
            __syncthreads();
            #pragma unroll
            for (int k = 0; k < 8; ++k) {
                int i = base + k * 256 + tid;
                int L = flag64 ? lab[2 * i] : lab[i];
                if (L == c) list[atomicAdd(&lcnt, 1)] = i;
            }
            __syncthreads();
            int n = lcnt;
            int j = stream;
            float v = (j < n) ? emb[(size_t)list[j] * N_D + d] : 0.f;
            while (j < n) {
                int jn = j + 2;
                float vn = (jn < n) ? emb[(size_t)list[jn] * N_D + d] : 0.f;
                acc += v;
                v = vn; j = jn;
            }
            total += n;
            __syncthreads();
        }
        if (stream == 1) tmp[d] = acc;
        __syncthreads();
        if (stream == 0) {
            ((float*)(ws + S_OFF))[c * N_D + d] = acc + tmp[d];
            if (d == 0) ((float*)(ws + CNT_OFF))[c] = (float)total;
        }
        return;
    }
    // misc block: flag + zero se + zero all counters
    {
        int flag64 = detect_i64(lab, N);
        float* se = (float*)(ws + SE_OFF);
        for (int i = tid; i < N; i += 256) se[i] = 0.f;
        int* ctrs = (int*)(ws + CTR_OFF);
        if (tid < 256) ctrs[tid] = (tid == 0) ? flag64 : 0;
    }
}

// ====== k_main: barrier-free, LDS-free; A pinned in regs, B streamed from L2 ======
// 512 blocks x 4 waves; wave w = bid*4+wv: rowgroup rg = w>>4 (64 rows), colgroup cg = w&15 (512 cols)
__global__ __launch_bounds__(256, 2) void k_main(const float* __restrict__ emb,
                                                 const int* __restrict__ lab,
                                                 char* __restrict__ ws,
                                                 float* __restrict__ out, int N) {
    const char* ebf = ws + EBF_OFF;
    float* se_ws = (float*)(ws + SE_OFF);
    int* ctrs = (int*)(ws + CTR_OFF);

    const int tid = threadIdx.x;
    const int lane = tid & 63;
    const int wv = tid >> 6;
    const int w = blockIdx.x * 4 + wv;     // 0..2047
    const int rg = w >> 4;                 // 0..127
    const int cg = w & 15;                 // 0..15
    const int rowbase = rg * 64;
    const int colbase = cg * 512;
    const int l15 = lane & 15, lhi = lane >> 4;
    const int xh = l15 << 4;               // swizzle XOR (row&15 == l15 for all our rows/cols)

    // ---- A fragments from pre-swizzled global, pinned resident (64 VGPRs) ----
    bf16x8 aF[4][4];   // [rf][ks]
    #pragma unroll
    for (int rf = 0; rf < 4; ++rf) {
        const char* rb = ebf + ((size_t)(rowbase + rf * 16 + l15) << 8);
        #pragma unroll
        for (int ks = 0; ks < 4; ++ks) {
            aF[rf][ks] = *(const bf16x8*)(rb + ((ks * 64 + lhi * 16) ^ xh));
            asm volatile("" : "+v"(aF[rf][ks]));
        }
    }

#define LOADB(buf, c16)                                                        \
    {                                                                          \
        const char* bb = ebf + ((size_t)((c16) + l15) << 8);                   \
        buf[0] = *(const bf16x8*)(bb + ((0 * 64 + lhi * 16) ^ xh));            \
        buf[1] = *(const bf16x8*)(bb + ((1 * 64 + lhi * 16) ^ xh));            \
        buf[2] = *(const bf16x8*)(bb + ((2 * 64 + lhi * 16) ^ xh));            \
        buf[3] = *(const bf16x8*)(bb + ((3 * 64 + lhi * 16) ^ xh));            \
    }

    float se[4][4];
    #pragma unroll
    for (int rf = 0; rf < 4; ++rf)
        #pragma unroll
        for (int reg = 0; reg < 4; ++reg) se[rf][reg] = 0.f;

#define COMPUTE(buf, stv)                                                      \
    {                                                                          \
        f32x4 acc[4];                                                          \
        _Pragma("unroll")                                                      \
        for (int rf = 0; rf < 4; ++rf) acc[rf] = (f32x4){0.f, 0.f, 0.f, 0.f}; \
        _Pragma("unroll")                                                      \
        for (int ks = 0; ks < 4; ++ks)                                         \
            _Pragma("unroll")                                                  \
            for (int rf = 0; rf < 4; ++rf)                                     \
                acc[rf] = __builtin_amdgcn_mfma_f32_16x16x32_bf16(             \
                    aF[rf][ks], buf[ks], acc[rf], 0, 0, 0);                    \
        unsigned doff = (unsigned)(colbase + (stv) * 16 - rowbase);            \
        if (doff < 64u) {                                                      \
            _Pragma("unroll")                                                  \
            for (int rf = 0; rf < 4; ++rf)                                     \
                _Pragma("unroll")                                              \
                for (int reg = 0; reg < 4; ++reg) {                            \
                    float e = fast_exp2(acc[rf][reg]);                         \
                    int lrow = rf * 16 + lhi * 4 + reg;                        \
                    e = (lrow == (int)doff + l15) ? 0.f : e;                   \
                    se[rf][reg] += e;                                          \
                }                                                              \
        } else {                                                               \
            _Pragma("unroll")                                                  \
            for (int rf = 0; rf < 4; ++rf)                                     \
                _Pragma("unroll")                                              \
                for (int reg = 0; reg < 4; ++reg)                              \
                    se[rf][reg] += fast_exp2(acc[rf][reg]);                    \
        }                                                                      \
    }

    // ---- main loop: 32 subtiles of 16 cols, register ping-pong, NO barriers ----
    bf16x8 bA[4], bB[4];
    LOADB(bA, colbase);
    #pragma unroll 4
    for (int st = 0; st < 32; st += 2) {
        if (st + 1 < 32) LOADB(bB, colbase + (st + 1) * 16);
        COMPUTE(bA, st);
        if (st + 2 < 32) LOADB(bA, colbase + (st + 2) * 16);
        COMPUTE(bB, st + 1);
    }
#undef LOADB
#undef COMPUTE

    // ---- reduce over 16 col-lanes, one atomic per row ----
    #pragma unroll
    for (int m = 1; m < 16; m <<= 1)
        #pragma unroll
        for (int rf = 0; rf < 4; ++rf)
            #pragma unroll
            for (int reg = 0; reg < 4; ++reg)
                se[rf][reg] += __shfl_xor(se[rf][reg], m);
    if (l15 == 0) {
        #pragma unroll
        for (int rf = 0; rf < 4; ++rf)
            #pragma unroll
            for (int reg = 0; reg < 4; ++reg) {
                int row = rowbase + rf * 16 + lhi * 4 + reg;
                atomicAdd(&se_ws[row], se[rf][reg]);
            }
    }
    __threadfence();

    // ---- fused tail: 16th finisher wave of this rowgroup computes its 64 rows ----
    int last = 0;
    if (lane == 0) last = (atomicAdd(&ctrs[8 + rg], 1) == 15) ? 1 : 0;
    last = __shfl(last, 0);
    if (!last) return;

    const int flag64 = ctrs[0];
    const int row = rowbase + lane;
    int L = flag64 ? lab[2 * row] : lab[row];
    const float* Sr = (const float*)(ws + S_OFF) + L * N_D;
    const float* er = emb + (size_t)row * N_D;
    float dot = 0.f, nrm = 0.f;
    #pragma unroll 8
    for (int k = 0; k < N_D; k += 4) {
        float4 e = *(const float4*)(er + k);
        float4 s4 = *(const float4*)(Sr + k);
        dot += e.x * s4.x + e.y * s4.y + e.z * s4.z + e.w * s4.w;
        nrm += e.x * e.x + e.y * e.y + e.z * e.z + e.w * e.w;
    }
    float pc = ((const float*)(ws + CNT_OFF))[L] - 1.f;
    float sev = __hip_atomic_load(&se_ws[row], __ATOMIC_RELAXED, __HIP_MEMORY_SCOPE_AGENT);
    float contrib = 0.f;
    if (pc > 0.f)
        contrib = ((dot - nrm) * TEMP_INV - pc * logf(sev + 1e-9f)) / pc;
    #pragma unroll
    for (int m = 1; m < 64; m <<= 1) contrib += __shfl_xor(contrib, m);
    if (lane == 0) {
        atomicAdd((float*)&ctrs[1], contrib);
        __threadfence();
        if (atomicAdd(&ctrs[2], 1) == 127) {
            float fin = atomicAdd((float*)&ctrs[1], 0.0f);   // device-scope read
            out[0] = -fin / (float)N;
        }
    }
}

// ======================= fallback (round-2 proven path) =======================
#define FBI 128
#define FBJ 64
#define FNSPLIT 8

__global__ void fb_prep(const int* __restrict__ lab32, float* __restrict__ ws, int N) {
    int tid = blockIdx.x * blockDim.x + threadIdx.x;
    int total = 3 * N;
    for (int i = tid; i < total; i += gridDim.x * blockDim.x) ws[i] = 0.0f;
    if (blockIdx.x == 0) {
        __shared__ int nz;
        if (threadIdx.x == 0) nz = 0;
        __syncthreads();
        int local = 0;
        int half = N >> 1;
        for (int i = threadIdx.x; i < half; i += blockDim.x)
            if (lab32[2 * i + 1] != 0) local = 1;
        if (local) atomicOr(&nz, 1);
        __syncthreads();
        if (threadIdx.x == 0) ((int*)ws)[3 * N] = (nz == 0) ? 1 : 0;
    }
}

__global__ __launch_bounds__(256) void fb_main(const float* __restrict__ emb,
                                               const int* __restrict__ lab32,
                                               float* __restrict__ ws, int N) {
    __shared__ ushort Ash[FBI * N_D];
    __shared__ ushort Bsh[FBJ * N_D];
    __shared__ int labA[FBI];
    __shared__ int labB[FBJ];

    const int tid  = threadIdx.x;
    const int lane = tid & 63;
    const int wave = tid >> 6;
    const int wr = wave >> 1;
    const int wc = wave & 1;
    const int l15 = lane & 15;
    const int lhi = lane >> 4;
    const int rowbase  = blockIdx.x * FBI;
    const int colsPer  = N / FNSPLIT;
    const int colstart = blockIdx.y * colsPer;
    const int flag64 = ((const int*)ws)[3 * N];

    for (int id = tid; id < FBI * 32; id += 256) {
        int row = id >> 5, k4 = id & 31;
        float4 v = *(const float4*)&emb[(size_t)(rowbase + row) * N_D + (k4 << 2)];
        uint p0 = (uint)f2bf(v.x) | ((uint)f2bf(v.y) << 16);
        uint p1 = (uint)f2bf(v.z) | ((uint)f2bf(v.w) << 16);
        int byte = (row << 8) + (k4 << 3);
        byte ^= (row & 7) << 4;
        *(uint2*)((char*)Ash + byte) = make_uint2(p0, p1);
    }
    if (tid < FBI) {
        int g = rowbase + tid;
        labA[tid] = flag64 ? lab32[2 * g] : lab32[g];
    }
    __syncthreads();

    int labR[4][4];
    const int rowc = rowbase + wr * 64 + lhi * 4;
    #pragma unroll
    for (int rf = 0; rf < 4; ++rf)
        #pragma unroll
        for (int reg = 0; reg < 4; ++reg)
            labR[rf][reg] = labA[wr * 64 + rf * 16 + lhi * 4 + reg];

    float se[4][4], ps[4][4], pc[4][4];
    #pragma unroll
    for (int rf = 0; rf < 4; ++rf)
        #pragma unroll
        for (int reg = 0; reg < 4; ++reg) { se[rf][reg] = 0.f; ps[rf][reg] = 0.f; pc[rf][reg] = 0.f; }

    for (int jt = colstart; jt < colstart + colsPer; jt += FBJ) {
        __syncthreads();
        for (int id = tid; id < FBJ * 32; id += 256) {
            int row = id >> 5, k4 = id & 31;
            float4 v = *(const float4*)&emb[(size_t)(jt + row) * N_D + (k4 << 2)];
            uint p0 = (uint)f2bf(v.x) | ((uint)f2bf(v.y) << 16);
            uint p1 = (uint)f2bf(v.z) | ((uint)f2bf(v.w) << 16);
            int byte = (row << 8) + (k4 << 3);
            byte ^= (row & 7) << 4;
            *(uint2*)((char*)Bsh + byte) = make_uint2(p0, p1);
        }
        if (tid < FBJ) {
            int g = jt + tid;
            labB[tid] = flag64 ? lab32[2 * g] : lab32[g];
        }
        __syncthreads();

        f32x4 zero4 = {0.f, 0.f, 0.f, 0.f};
        f32x4 acc[4][2];
        #pragma unroll
        for (int rf = 0; rf < 4; ++rf)
            #pragma unroll
            for (int cf = 0; cf < 2; ++cf) acc[rf][cf] = zero4;

        const int kbyteBase = lhi * 16;
        #pragma unroll
        for (int ks = 0; ks < 4; ++ks) {
            int kb = ks * 64 + kbyteBase;
            bf16x8 aF[4], bF[2];
            #pragma unroll
            for (int rf = 0; rf < 4; ++rf) {
                int row = wr * 64 + rf * 16 + l15;
                int byte = (row << 8) + kb;
                byte ^= (row & 7) << 4;
                aF[rf] = *(bf16x8*)((char*)Ash + byte);
            }
            #pragma unroll
            for (int cf = 0; cf < 2; ++cf) {
                int col = wc * 32 + cf * 16 + l15;
                int byte = (col << 8) + kb;
                byte ^= (col & 7) << 4;
                bF[cf] = *(bf16x8*)((char*)Bsh + byte);
            }
            #pragma unroll
            for (int rf = 0; rf < 4; ++rf)
                #pragma unroll
                for (int cf = 0; cf < 2; ++cf)
                    acc[rf][cf] = __builtin_amdgcn_mfma_f32_16x16x32_bf16(
                        aF[rf], bF[cf], acc[rf][cf], 0, 0, 0);
        }

        int labC[2], gcol[2];
        #pragma unroll
        for (int cf = 0; cf < 2; ++cf) {
            int col = wc * 32 + cf * 16 + l15;
            labC[cf] = labB[col];
            gcol[cf] = jt + col;
        }
        bool hasdiag = (jt < rowbase + FBI) && (jt + FBJ > rowbase);

#define EPILOGUE(HD)                                                          \
        _Pragma("unroll")                                                     \
        for (int cf = 0; cf < 2; ++cf) {                                      \
            _Pragma("unroll")                                                 \
            for (int rf = 0; rf < 4; ++rf) {                                  \
                _Pragma("unroll")                                             \
                for (int reg = 0; reg < 4; ++reg) {                           \
                    float sim = acc[rf][cf][reg] * TEMP_INV;                  \
                    float e = __expf(sim);                                    \
                    bool pos = (labR[rf][reg] == labC[cf]);                   \
                    if (HD) {                                                 \
                        bool diag = ((rowc + rf * 16 + reg) == gcol[cf]);     \
                        e = diag ? 0.f : e;                                   \
                        pos = pos && !diag;                                   \
                    }                                                         \
                    se[rf][reg] += e;                                         \
                    ps[rf][reg] += pos ? sim : 0.f;                           \
                    pc[rf][reg] += pos ? 1.f : 0.f;                           \
                }                                                             \
            }                                                                 \
        }

        if (hasdiag) { EPILOGUE(true) } else { EPILOGUE(false) }
#undef EPILOGUE
    }

    for (int m = 1; m < 16; m <<= 1) {
        #pragma unroll
        for (int rf = 0; rf < 4; ++rf)
            #pragma unroll
            for (int reg = 0; reg < 4; ++reg) {
                se[rf][reg] += __shfl_xor(se[rf][reg], m);
                ps[rf][reg] += __shfl_xor(ps[rf][reg], m);
                pc[rf][reg] += __shfl_xor(pc[rf][reg], m);
            }
    }
    if (l15 == 0) {
        #pragma unroll
        for (int rf = 0; rf < 4; ++rf)
            #pragma unroll
            for (int reg = 0; reg < 4; ++reg) {
                int row = rowc + rf * 16 + reg;
                atomicAdd(&ws[row],         se[rf][reg]);
                atomicAdd(&ws[N + row],     ps[rf][reg]);
                atomicAdd(&ws[2 * N + row], pc[rf][reg]);
            }
    }
}

__global__ void fb_final(const float* __restrict__ ws, float* __restrict__ out, int N) {
    __shared__ float red[256];
    float local = 0.0f;
    for (int i = threadIdx.x; i < N; i += 256) {
        float sev = ws[i], psv = ws[N + i], pcv = ws[2 * N + i];
        float lp = psv - pcv * logf(sev + 1e-9f);
        float denom = (pcv == 0.0f) ? 1.0f : pcv;
        local += lp / denom;
    }
    red[threadIdx.x] = local;
    __syncthreads();
    for (int s = 128; s > 0; s >>= 1) {
        if (threadIdx.x < s) red[threadIdx.x] += red[threadIdx.x + s];
        __syncthreads();
    }
    if (threadIdx.x == 0) out[0] = -red[0] / (float)N;
}

// ======================= launcher =======================
extern "C" void kernel_launch(void* const* d_in, const int* in_sizes, int n_in,
                              void* d_out, int out_size, void* d_ws, size_t ws_size,
                              hipStream_t stream) {
    const float* emb = (const float*)d_in[0];
    const int* lab = (const int*)d_in[1];
    float* out = (float*)d_out;
    const int N = in_sizes[0] / N_D;

    if (N == 8192 && ws_size >= (size_t)WS_NEEDED) {
        char* ws = (char*)d_ws;
        hipLaunchKernelGGL(k_pre, dim3(613), dim3(256), 0, stream, emb, lab, ws, N);
        hipLaunchKernelGGL(k_main, dim3(512), dim3(256), 0, stream, emb, lab, ws, out, N);
    } else {
        float* ws = (float*)d_ws;
        hipLaunchKernelGGL(fb_prep, dim3(32), dim3(256), 0, stream, lab, ws, N);
        dim3 grid(N / FBI, FNSPLIT);
        hipLaunchKernelGGL(fb_main, grid, dim3(256), 0, stream, emb, lab, ws, N);
        hipLaunchKernelGGL(fb_final, dim3(1), dim3(256), 0, stream, ws, out, N);
    }
}

// Round 10
// 91.223 us; speedup vs baseline: 1.1171x; 1.1171x over previous
//
#include <hip/hip_runtime.h>
#include <hip/hip_bf16.h>
#include <math.h>

#define N_D 128
#define TEMP_INV 14.285714285714286f
#define EXP2_SCALE 20.60992915555662f   // (1/0.07) * log2(e)
#define SQRT_E2S 4.539816f              // sqrt(EXP2_SCALE); folded into bf16 data

using bf16x8 = __attribute__((ext_vector_type(8))) short;
using f32x4  = __attribute__((ext_vector_type(4))) float;

// ---------------- ws layout (bytes), N=8192 fast path ----------------
#define EBF_OFF   0u          // 8192*128 bf16, PRE-SWIZZLED rows, PRE-SCALED by SQRT_E2S (2 MB)
#define SE_OFF    2097152u    // 8192 f32 row exp-sums (zeroed by k_pre misc block)
#define S_OFF     2129920u    // 100*128 f32 class sums (raw emb)
#define CNT_OFF   2181120u    // 100 f32 class counts
#define CTR_OFF   2181632u    // 256 ints: [0]=flag64 [1]=FIN(f32) [2]=DONE [8+rb]=rowblock ctr
#define WS_NEEDED 2182656u

__device__ __forceinline__ ushort f2bf(float f) {
    __hip_bfloat16 h = __float2bfloat16(f);
    return *reinterpret_cast<ushort*>(&h);
}

__device__ __forceinline__ float fast_exp2(float x) {
#if __has_builtin(__builtin_amdgcn_exp2f)
    return __builtin_amdgcn_exp2f(x);
#else
    float r; asm("v_exp_f32 %0, %1" : "=v"(r) : "v"(x)); return r;
#endif
}

__device__ __forceinline__ void glds16(const void* src, void* dst) {
    __builtin_amdgcn_global_load_lds(
        (const __attribute__((address_space(1))) unsigned int*)src,
        (__attribute__((address_space(3))) unsigned int*)dst, 16, 0, 0);
}

__device__ int detect_i64(const int* lab, int N) {
    __shared__ int s_any;
    if (threadIdx.x == 0) s_any = 0;
    __syncthreads();
    int any = 0;
    for (int i = threadIdx.x; i < (N >> 1); i += blockDim.x)
        any |= (lab[2 * i + 1] != 0);
    if (__any(any) && (threadIdx.x & 63) == 0) atomicOr(&s_any, 1);
    __syncthreads();
    return s_any ? 0 : 1;   // all odd words zero => int64
}

// ====== k_pre: [0,512) bf16 convert (pre-swizzled, pre-scaled) | [512,612) class sums | 612 misc ======
__global__ __launch_bounds__(256) void k_pre(const float* __restrict__ emb,
                                             const int* __restrict__ lab,
                                             char* __restrict__ ws, int N) {
    __shared__ int list[1024];
    __shared__ int lcnt;
    __shared__ float tmp[128];
    const int blk = blockIdx.x;
    const int tid = threadIdx.x;

    if (blk < 512) {
        // convert: id -> row g, slot s; store orig[g][s ^ (g&15)] at [g][s], scaled
        int id = blk * 256 + tid;            // 0 .. 131071
        int g = id >> 4, s = id & 15;
        int srcslot = s ^ (g & 15);
        const float* src = emb + (size_t)g * N_D + srcslot * 8;
        float4 v0 = *(const float4*)src;
        float4 v1 = *(const float4*)(src + 4);
        uint4 o;
        o.x = (uint)f2bf(v0.x * SQRT_E2S) | ((uint)f2bf(v0.y * SQRT_E2S) << 16);
        o.y = (uint)f2bf(v0.z * SQRT_E2S) | ((uint)f2bf(v0.w * SQRT_E2S) << 16);
        o.z = (uint)f2bf(v1.x * SQRT_E2S) | ((uint)f2bf(v1.y * SQRT_E2S) << 16);
        o.w = (uint)f2bf(v1.z * SQRT_E2S) | ((uint)f2bf(v1.w * SQRT_E2S) << 16);
        ((uint4*)(ws + EBF_OFF))[id] = o;
        return;
    }
    if (blk < 612) {
        // class-sum for class c: one full-N index list, then 8-deep ILP row sums
        int c = blk - 512;
        int flag64 = detect_i64(lab, N);
        if (tid == 0) lcnt = 0;
        __syncthreads();
        for (int i = tid; i < N; i += 256) {
            int L = flag64 ? lab[2 * i] : lab[i];
            if (L == c) list[atomicAdd(&lcnt, 1) & 1023] = i;
        }
        __syncthreads();
        int n = lcnt; if (n > 1024) n = 1024;
        int stream = tid >> 7;      // 0/1
        int d = tid & 127;
        float acc = 0.f;
        int j = stream;
        while (j + 14 < n) {        // 8 independent loads in flight
            float t0 = emb[(size_t)list[j     ] * N_D + d];
            float t1 = emb[(size_t)list[j +  2] * N_D + d];
            float t2 = emb[(size_t)list[j +  4] * N_D + d];
            float t3 = emb[(size_t)list[j +  6] * N_D + d];
            float t4 = emb[(size_t)list[j +  8] * N_D + d];
            float t5 = emb[(size_t)list[j + 10] * N_D + d];
            float t6 = emb[(size_t)list[j + 12] * N_D + d];
            float t7 = emb[(size_t)list[j + 14] * N_D + d];
            acc += ((t0 + t1) + (t2 + t3)) + ((t4 + t5) + (t6 + t7));
            j += 16;
        }
        for (; j < n; j += 2) acc += emb[(size_t)list[j] * N_D + d];
        if (stream == 1) tmp[d] = acc;
        __syncthreads();
        if (stream == 0) {
            ((float*)(ws + S_OFF))[c * N_D + d] = acc + tmp[d];
            if (d == 0) ((float*)(ws + CNT_OFF))[c] = (float)n;
        }
        return;
    }
    // misc block: flag + zero se + zero all counters
    {
        int flag64 = detect_i64(lab, N);
        float* se = (float*)(ws + SE_OFF);
        for (int i = tid; i < N; i += 256) se[i] = 0.f;
        int* ctrs = (int*)(ws + CTR_OFF);
        if (tid < 256) ctrs[tid] = (tid == 0) ? flag64 : 0;
    }
}

// ====== k_main (r6 structure): A glds->LDS->regs, B 2x16KB dbuf, 1 barrier/iter, fused tail ======
__global__ __launch_bounds__(256, 3) void k_main(const float* __restrict__ emb,
                                                 const int* __restrict__ lab,
                                                 char* __restrict__ ws,
                                                 float* __restrict__ out, int N) {
    __shared__ __attribute__((aligned(128))) char smem[32768];  // buf0/buf1 16KB each
    __shared__ int s_last;

    const char* ebf = ws + EBF_OFF;
    float* se_ws = (float*)(ws + SE_OFF);
    int* ctrs = (int*)(ws + CTR_OFF);

    const int bid = blockIdx.x;            // 768 = 64 rowblocks x 12 splits
    const int rowblk = bid & 63;           // bid%8 = rowblk%8 -> rowblock pinned to one XCD
    const int s12 = bid >> 6;
    const int rowbase = rowblk * 128;
    const int t0 = (s12 * 128) / 12;       // 64-col tile range [t0,t1)
    const int t1 = ((s12 + 1) * 128) / 12;

    const int tid = threadIdx.x;
    const int lane = tid & 63;
    const int wave = tid >> 6;
    const int wr = wave >> 1, wc = wave & 1;   // 2x2: 64 rows x 32 cols per wave
    const int l15 = lane & 15, lhi = lane >> 4;

    // ---- stage A (128 x 256B = 32 KB) across both bufs ----
    {
        const char* src = ebf + ((size_t)(rowbase + wave * 32 + lhi) << 8) + (l15 << 4);
        char* dst = smem + wave * 8192;
        #pragma unroll
        for (int i = 0; i < 8; ++i) glds16(src + i * 1024, dst + i * 1024);
    }
    __syncthreads();
    // ---- hoist A fragments to registers (barriers order LDS ops -> real hoist) ----
    bf16x8 aF[4][4];   // [rf][ks] = 64 VGPRs
    #pragma unroll
    for (int rf = 0; rf < 4; ++rf) {
        int row = wr * 64 + rf * 16 + l15;
        #pragma unroll
        for (int ks = 0; ks < 4; ++ks)
            aF[rf][ks] = *(const bf16x8*)(smem + row * 256 + ((ks * 64 + lhi * 16) ^ (l15 << 4)));
    }
    __syncthreads();   // all hoists done, bufs free

    // ---- prologue: stage B(t0) into buf0 ----
    {
        const char* src = ebf + ((size_t)(t0 * 64 + wave * 16 + lhi) << 8) + (l15 << 4);
        char* dst = smem + wave * 4096;
        #pragma unroll
        for (int i = 0; i < 4; ++i) glds16(src + i * 1024, dst + i * 1024);
    }
    __syncthreads();   // B(t0) resident

    float se[4][4];
    #pragma unroll
    for (int rf = 0; rf < 4; ++rf)
        #pragma unroll
        for (int reg = 0; reg < 4; ++reg) se[rf][reg] = 0.f;

    int pb = 0;
    for (int t = t0; t < t1; ++t) {
        if (t + 1 < t1) {   // stage next tile first (overlaps compute)
            const char* src = ebf + ((size_t)((t + 1) * 64 + wave * 16 + lhi) << 8) + (l15 << 4);
            char* dst = smem + (pb ^ 1) * 16384 + wave * 4096;
            #pragma unroll
            for (int i = 0; i < 4; ++i) glds16(src + i * 1024, dst + i * 1024);
        }
        const char* cur = smem + pb * 16384;

        f32x4 acc[4][2];
        #pragma unroll
        for (int rf = 0; rf < 4; ++rf)
            #pragma unroll
            for (int cf = 0; cf < 2; ++cf) acc[rf][cf] = (f32x4){0.f, 0.f, 0.f, 0.f};

        #pragma unroll
        for (int ks = 0; ks < 4; ++ks) {
            const int kb = (ks * 64 + lhi * 16) ^ (l15 << 4);
            bf16x8 bF[2];
            #pragma unroll
            for (int cf = 0; cf < 2; ++cf) {
                int col = wc * 32 + cf * 16 + l15;
                bF[cf] = *(const bf16x8*)(cur + col * 256 + kb);
            }
            #pragma unroll
            for (int rf = 0; rf < 4; ++rf)
                #pragma unroll
                for (int cf = 0; cf < 2; ++cf)
                    acc[rf][cf] = __builtin_amdgcn_mfma_f32_16x16x32_bf16(
                        aF[rf][ks], bF[cf], acc[rf][cf], 0, 0, 0);
        }

        // epilogue: acc already = sim * log2e / T (pre-scaled data); one exp2 + add per elem
        unsigned dgu = (unsigned)(t * 64 - rowbase);

#define EPILOGUE(HD)                                                          \
        _Pragma("unroll")                                                     \
        for (int rf = 0; rf < 4; ++rf)                                        \
            _Pragma("unroll")                                                 \
            for (int cf = 0; cf < 2; ++cf)                                    \
                _Pragma("unroll")                                             \
                for (int reg = 0; reg < 4; ++reg) {                           \
                    float e = fast_exp2(acc[rf][cf][reg]);                    \
                    if (HD) {                                                 \
                        int lrow = wr * 64 + rf * 16 + lhi * 4 + reg;         \
                        int lcol = (int)dgu + wc * 32 + cf * 16 + l15;        \
                        e = (lrow == lcol) ? 0.f : e;                         \
                    }                                                         \
                    se[rf][reg] += e;                                         \
                }

        if (dgu < 128u) { EPILOGUE(true) } else { EPILOGUE(false) }
#undef EPILOGUE

        __syncthreads();   // next tile landed + all waves done with cur
        pb ^= 1;
    }

    // ---- reduce over 16 col-lanes, one atomic per row ----
    #pragma unroll
    for (int m = 1; m < 16; m <<= 1)
        #pragma unroll
        for (int rf = 0; rf < 4; ++rf)
            #pragma unroll
            for (int reg = 0; reg < 4; ++reg)
                se[rf][reg] += __shfl_xor(se[rf][reg], m);
    if (l15 == 0) {
        #pragma unroll
        for (int rf = 0; rf < 4; ++rf)
            #pragma unroll
            for (int reg = 0; reg < 4; ++reg) {
                int row = rowbase + wr * 64 + rf * 16 + lhi * 4 + reg;
                atomicAdd(&se_ws[row], se[rf][reg]);
            }
    }
    __threadfence();
    __syncthreads();

    // ---- fused tail: 12th finisher of this rowblock computes its 128 rows ----
    if (tid == 0) s_last = (atomicAdd(&ctrs[8 + rowblk], 1) == 11) ? 1 : 0;
    __syncthreads();
    if (!s_last) return;

    const int flag64 = ctrs[0];
    const int r = rowbase + (tid >> 1);
    const int half = tid & 1;
    int L = flag64 ? lab[2 * r] : lab[r];
    const float* Sr = (const float*)(ws + S_OFF) + L * N_D + half * 64;
    const float* er = emb + (size_t)r * N_D + half * 64;
    float dot = 0.f, nrm = 0.f;
    #pragma unroll 8
    for (int k = 0; k < 64; k += 4) {
        float4 e = *(const float4*)(er + k);
        float4 s4 = *(const float4*)(Sr + k);
        dot += e.x * s4.x + e.y * s4.y + e.z * s4.z + e.w * s4.w;
        nrm += e.x * e.x + e.y * e.y + e.z * e.z + e.w * e.w;
    }
    dot += __shfl_xor(dot, 1);
    nrm += __shfl_xor(nrm, 1);
    float contrib = 0.f;
    if (half == 0) {
        float pc = ((const float*)(ws + CNT_OFF))[L] - 1.f;
        float sev = __hip_atomic_load(&se_ws[r], __ATOMIC_RELAXED, __HIP_MEMORY_SCOPE_AGENT);
        if (pc > 0.f)
            contrib = ((dot - nrm) * TEMP_INV - pc * logf(sev + 1e-9f)) / pc;
    }
    float* red = (float*)smem;
    red[tid] = contrib;
    __syncthreads();
    for (int s = 128; s > 0; s >>= 1) {
        if (tid < s) red[tid] += red[tid + s];
        __syncthreads();
    }
    if (tid == 0) {
        atomicAdd((float*)&ctrs[1], red[0]);
        __threadfence();
        if (atomicAdd(&ctrs[2], 1) == 63) {
            float fin = atomicAdd((float*)&ctrs[1], 0.0f);   // device-scope read
            out[0] = -fin / (float)N;
        }
    }
}

// ======================= fallback (round-2 proven path) =======================
#define FBI 128
#define FBJ 64
#define FNSPLIT 8

__global__ void fb_prep(const int* __restrict__ lab32, float* __restrict__ ws, int N) {
    int tid = blockIdx.x * blockDim.x + threadIdx.x;
    int total = 3 * N;
    for (int i = tid; i < total; i += gridDim.x * blockDim.x) ws[i] = 0.0f;
    if (blockIdx.x == 0) {
        __shared__ int nz;
        if (threadIdx.x == 0) nz = 0;
        __syncthreads();
        int local = 0;
        int half = N >> 1;
        for (int i = threadIdx.x; i < half; i += blockDim.x)
            if (lab32[2 * i + 1] != 0) local = 1;
        if (local) atomicOr(&nz, 1);
        __syncthreads();
        if (threadIdx.x == 0) ((int*)ws)[3 * N] = (nz == 0) ? 1 : 0;
    }
}

__global__ __launch_bounds__(256) void fb_main(const float* __restrict__ emb,
                                               const int* __restrict__ lab32,
                                               float* __restrict__ ws, int N) {
    __shared__ ushort Ash[FBI * N_D];
    __shared__ ushort Bsh[FBJ * N_D];
    __shared__ int labA[FBI];
    __shared__ int labB[FBJ];

    const int tid  = threadIdx.x;
    const int lane = tid & 63;
    const int wave = tid >> 6;
    const int wr = wave >> 1;
    const int wc = wave & 1;
    const int l15 = lane & 15;
    const int lhi = lane >> 4;
    const int rowbase  = blockIdx.x * FBI;
    const int colsPer  = N / FNSPLIT;
    const int colstart = blockIdx.y * colsPer;
    const int flag64 = ((const int*)ws)[3 * N];

    for (int id = tid; id < FBI * 32; id += 256) {
        int row = id >> 5, k4 = id & 31;
        float4 v = *(const float4*)&emb[(size_t)(rowbase + row) * N_D + (k4 << 2)];
        uint p0 = (uint)f2bf(v.x) | ((uint)f2bf(v.y) << 16);
        uint p1 = (uint)f2bf(v.z) | ((uint)f2bf(v.w) << 16);
        int byte = (row << 8) + (k4 << 3);
        byte ^= (row & 7) << 4;
        *(uint2*)((char*)Ash + byte) = make_uint2(p0, p1);
    }
    if (tid < FBI) {
        int g = rowbase + tid;
        labA[tid] = flag64 ? lab32[2 * g] : lab32[g];
    }
    __syncthreads();

    int labR[4][4];
    const int rowc = rowbase + wr * 64 + lhi * 4;
    #pragma unroll
    for (int rf = 0; rf < 4; ++rf)
        #pragma unroll
        for (int reg = 0; reg < 4; ++reg)
            labR[rf][reg] = labA[wr * 64 + rf * 16 + lhi * 4 + reg];

    float se[4][4], ps[4][4], pc[4][4];
    #pragma unroll
    for (int rf = 0; rf < 4; ++rf)
        #pragma unroll
        for (int reg = 0; reg < 4; ++reg) { se[rf][reg] = 0.f; ps[rf][reg] = 0.f; pc[rf][reg] = 0.f; }

    for (int jt = colstart; jt < colstart + colsPer; jt += FBJ) {
        __syncthreads();
        for (int id = tid; id < FBJ * 32; id += 256) {
            int row = id >> 5, k4 = id & 31;
            float4 v = *(const float4*)&emb[(size_t)(jt + row) * N_D + (k4 << 2)];
            uint p0 = (uint)f2bf(v.x) | ((uint)f2bf(v.y) << 16);
            uint p1 = (uint)f2bf(v.z) | ((uint)f2bf(v.w) << 16);
            int byte = (row << 8) + (k4 << 3);
            byte ^= (row & 7) << 4;
            *(uint2*)((char*)Bsh + byte) = make_uint2(p0, p1);
        }
        if (tid < FBJ) {
            int g = jt + tid;
            labB[tid] = flag64 ? lab32[2 * g] : lab32[g];
        }
        __syncthreads();

        f32x4 zero4 = {0.f, 0.f, 0.f, 0.f};
        f32x4 acc[4][2];
        #pragma unroll
        for (int rf = 0; rf < 4; ++rf)
            #pragma unroll
            for (int cf = 0; cf < 2; ++cf) acc[rf][cf] = zero4;

        const int kbyteBase = lhi * 16;
        #pragma unroll
        for (int ks = 0; ks < 4; ++ks) {
            int kb = ks * 64 + kbyteBase;
            bf16x8 aF[4], bF[2];
            #pragma unroll
            for (int rf = 0; rf < 4; ++rf) {
                int row = wr * 64 + rf * 16 + l15;
                int byte = (row << 8) + kb;
                byte ^= (row & 7) << 4;
                aF[rf] = *(bf16x8*)((char*)Ash + byte);
            }
            #pragma unroll
            for (int cf = 0; cf < 2; ++cf) {
                int col = wc * 32 + cf * 16 + l15;
                int byte = (col << 8) + kb;
                byte ^= (col & 7) << 4;
                bF[cf] = *(bf16x8*)((char*)Bsh + byte);
            }
            #pragma unroll
            for (int rf = 0; rf < 4; ++rf)
                #pragma unroll
                for (int cf = 0; cf < 2; ++cf)
                    acc[rf][cf] = __builtin_amdgcn_mfma_f32_16x16x32_bf16(
                        aF[rf], bF[cf], acc[rf][cf], 0, 0, 0);
        }

        int labC[2], gcol[2];
        #pragma unroll
        for (int cf = 0; cf < 2; ++cf) {
            int col = wc * 32 + cf * 16 + l15;
            labC[cf] = labB[col];
            gcol[cf] = jt + col;
        }
        bool hasdiag = (jt < rowbase + FBI) && (jt + FBJ > rowbase);

#define EPILOGUE(HD)                                                          \
        _Pragma("unroll")                                                     \
        for (int cf = 0; cf < 2; ++cf) {                                      \
            _Pragma("unroll")                                                 \
            for (int rf = 0; rf < 4; ++rf) {                                  \
                _Pragma("unroll")                                             \
                for (int reg = 0; reg < 4; ++reg) {                           \
                    float sim = acc[rf][cf][reg] * TEMP_INV;                  \
                    float e = __expf(sim);                                    \
                    bool pos = (labR[rf][reg] == labC[cf]);                   \
                    if (HD) {                                                 \
                        bool diag = ((rowc + rf * 16 + reg) == gcol[cf]);     \
                        e = diag ? 0.f : e;                                   \
                        pos = pos && !diag;                                   \
                    }                                                         \
                    se[rf][reg] += e;                                         \
                    ps[rf][reg] += pos ? sim : 0.f;                           \
                    pc[rf][reg] += pos ? 1.f : 0.f;                           \
                }                                                             \
            }                                                                 \
        }

        if (hasdiag) { EPILOGUE(true) } else { EPILOGUE(false) }
#undef EPILOGUE
    }

    for (int m = 1; m < 16; m <<= 1) {
        #pragma unroll
        for (int rf = 0; rf < 4; ++rf)
            #pragma unroll
            for (int reg = 0; reg < 4; ++reg) {
                se[rf][reg] += __shfl_xor(se[rf][reg], m);
                ps[rf][reg] += __shfl_xor(ps[rf][reg], m);
                pc[rf][reg] += __shfl_xor(pc[rf][reg], m);
            }
    }
    if (l15 == 0) {
        #pragma unroll
        for (int rf = 0; rf < 4; ++rf)
            #pragma unroll
            for (int reg = 0; reg < 4; ++reg) {
                int row = rowc + rf * 16 + reg;
                atomicAdd(&ws[row],         se[rf][reg]);
                atomicAdd(&ws[N + row],     ps[rf][reg]);
                atomicAdd(&ws[2 * N + row], pc[rf][reg]);
            }
    }
}

__global__ void fb_final(const float* __restrict__ ws, float* __restrict__ out, int N) {
    __shared__ float red[256];
    float local = 0.0f;
    for (int i = threadIdx.x; i < N; i += 256) {
        float sev = ws[i], psv = ws[N + i], pcv = ws[2 * N + i];
        float lp = psv - pcv * logf(sev + 1e-9f);
        float denom = (pcv == 0.0f) ? 1.0f : pcv;
        local += lp / denom;
    }
    red[threadIdx.x] = local;
    __syncthreads();
    for (int s = 128; s > 0; s >>= 1) {
        if (threadIdx.x < s) red[threadIdx.x] += red[threadIdx.x + s];
        __syncthreads();
    }
    if (threadIdx.x == 0) out[0] = -red[0] / (float)N;
}

// ======================= launcher =======================
extern "C" void kernel_launch(void* const* d_in, const int* in_sizes, int n_in,
                              void* d_out, int out_size, void* d_ws, size_t ws_size,
                              hipStream_t stream) {
    const float* emb = (const float*)d_in[0];
    const int* lab = (const int*)d_in[1];
    float* out = (float*)d_out;
    const int N = in_sizes[0] / N_D;

    if (N == 8192 && ws_size >= (size_t)WS_NEEDED) {
        char* ws = (char*)d_ws;
        hipLaunchKernelGGL(k_pre, dim3(613), dim3(256), 0, stream, emb, lab, ws, N);
        hipLaunchKernelGGL(k_main, dim3(768), dim3(256), 0, stream, emb, lab, ws, out, N);
    } else {
        float* ws = (float*)d_ws;
        hipLaunchKernelGGL(fb_prep, dim3(32), dim3(256), 0, stream, lab, ws, N);
        dim3 grid(N / FBI, FNSPLIT);
        hipLaunchKernelGGL(fb_main, grid, dim3(256), 0, stream, emb, lab, ws, N);
        hipLaunchKernelGGL(fb_final, dim3(1), dim3(256), 0, stream, ws, out, N);
    }
}

// Round 11
// 53.055 us; speedup vs baseline: 1.9207x; 1.7194x over previous
//
#include <hip/hip_runtime.h>
#include <hip/hip_bf16.h>
#include <math.h>

#define N_D 128
#define TEMP_INV 14.285714285714286f
#define EXP2_SCALE 20.60992915555662f   // (1/0.07) * log2(e)
#define SQRT_E2S 4.539816f              // sqrt(EXP2_SCALE); folded into bf16 data

using bf16x8 = __attribute__((ext_vector_type(8))) short;
using f32x4  = __attribute__((ext_vector_type(4))) float;

// ---------------- ws layout (bytes), N=8192 fast path ----------------
#define EBF_OFF   0u          // 8192*128 bf16, PRE-SWIZZLED rows, PRE-SCALED by SQRT_E2S (2 MB)
#define SE_OFF    2097152u    // 8192 f32 row exp-sums (zeroed by k_pre misc block)
#define S_OFF     2129920u    // 100*128 f32 class sums (raw emb)
#define CNT_OFF   2181120u    // 100 f32 class counts
#define CTR_OFF   2181632u    // 256 ints: [0]=flag64 [1]=FIN(f32) [2]=DONE
#define WS_NEEDED 2182656u

__device__ __forceinline__ ushort f2bf(float f) {
    __hip_bfloat16 h = __float2bfloat16(f);
    return *reinterpret_cast<ushort*>(&h);
}

__device__ __forceinline__ float fast_exp2(float x) {
#if __has_builtin(__builtin_amdgcn_exp2f)
    return __builtin_amdgcn_exp2f(x);
#else
    float r; asm("v_exp_f32 %0, %1" : "=v"(r) : "v"(x)); return r;
#endif
}

__device__ __forceinline__ void glds16(const void* src, void* dst) {
    __builtin_amdgcn_global_load_lds(
        (const __attribute__((address_space(1))) unsigned int*)src,
        (__attribute__((address_space(3))) unsigned int*)dst, 16, 0, 0);
}

__device__ int detect_i64(const int* lab, int N) {
    __shared__ int s_any;
    if (threadIdx.x == 0) s_any = 0;
    __syncthreads();
    int any = 0;
    for (int i = threadIdx.x; i < (N >> 1); i += blockDim.x)
        any |= (lab[2 * i + 1] != 0);
    if (__any(any) && (threadIdx.x & 63) == 0) atomicOr(&s_any, 1);
    __syncthreads();
    return s_any ? 0 : 1;   // all odd words zero => int64
}

// ====== k_pre: [0,512) bf16 convert (pre-swizzled, pre-scaled) | [512,612) class sums | 612 misc ======
__global__ __launch_bounds__(256) void k_pre(const float* __restrict__ emb,
                                             const int* __restrict__ lab,
                                             char* __restrict__ ws, int N) {
    __shared__ int list[1024];
    __shared__ int lcnt;
    __shared__ float tmp[128];
    const int blk = blockIdx.x;
    const int tid = threadIdx.x;

    if (blk < 512) {
        // convert: id -> row g, slot s; store orig[g][s ^ (g&15)] at [g][s], scaled
        int id = blk * 256 + tid;            // 0 .. 131071
        int g = id >> 4, s = id & 15;
        int srcslot = s ^ (g & 15);
        const float* src = emb + (size_t)g * N_D + srcslot * 8;
        float4 v0 = *(const float4*)src;
        float4 v1 = *(const float4*)(src + 4);
        uint4 o;
        o.x = (uint)f2bf(v0.x * SQRT_E2S) | ((uint)f2bf(v0.y * SQRT_E2S) << 16);
        o.y = (uint)f2bf(v0.z * SQRT_E2S) | ((uint)f2bf(v0.w * SQRT_E2S) << 16);
        o.z = (uint)f2bf(v1.x * SQRT_E2S) | ((uint)f2bf(v1.y * SQRT_E2S) << 16);
        o.w = (uint)f2bf(v1.z * SQRT_E2S) | ((uint)f2bf(v1.w * SQRT_E2S) << 16);
        ((uint4*)(ws + EBF_OFF))[id] = o;
        return;
    }
    if (blk < 612) {
        // class-sum for class c: one full-N index list, then 8-deep ILP row sums
        int c = blk - 512;
        int flag64 = detect_i64(lab, N);
        if (tid == 0) lcnt = 0;
        __syncthreads();
        for (int i = tid; i < N; i += 256) {
            int L = flag64 ? lab[2 * i] : lab[i];
            if (L == c) list[atomicAdd(&lcnt, 1) & 1023] = i;
        }
        __syncthreads();
        int n = lcnt; if (n > 1024) n = 1024;
        int stream = tid >> 7;      // 0/1
        int d = tid & 127;
        float acc = 0.f;
        int j = stream;
        while (j + 14 < n) {        // 8 independent loads in flight
            float t0 = emb[(size_t)list[j     ] * N_D + d];
            float t1 = emb[(size_t)list[j +  2] * N_D + d];
            float t2 = emb[(size_t)list[j +  4] * N_D + d];
            float t3 = emb[(size_t)list[j +  6] * N_D + d];
            float t4 = emb[(size_t)list[j +  8] * N_D + d];
            float t5 = emb[(size_t)list[j + 10] * N_D + d];
            float t6 = emb[(size_t)list[j + 12] * N_D + d];
            float t7 = emb[(size_t)list[j + 14] * N_D + d];
            acc += ((t0 + t1) + (t2 + t3)) + ((t4 + t5) + (t6 + t7));
            j += 16;
        }
        for (; j < n; j += 2) acc += emb[(size_t)list[j] * N_D + d];
        if (stream == 1) tmp[d] = acc;
        __syncthreads();
        if (stream == 0) {
            ((float*)(ws + S_OFF))[c * N_D + d] = acc + tmp[d];
            if (d == 0) ((float*)(ws + CNT_OFF))[c] = (float)n;
        }
        return;
    }
    // misc block: flag + zero se + zero all counters
    {
        int flag64 = detect_i64(lab, N);
        float* se = (float*)(ws + SE_OFF);
        for (int i = tid; i < N; i += 256) se[i] = 0.f;
        int* ctrs = (int*)(ws + CTR_OFF);
        if (tid < 256) ctrs[tid] = (tid == 0) ? flag64 : 0;
    }
}

// ====== k_main: (256,2), NO fused tail -- the proven-healthy allocator config ======
__global__ __launch_bounds__(256, 2) void k_main(char* __restrict__ ws, int N) {
    __shared__ __attribute__((aligned(128))) char smem[32768];  // buf0/buf1 16KB each

    const char* ebf = ws + EBF_OFF;
    float* se_ws = (float*)(ws + SE_OFF);

    const int bid = blockIdx.x;            // 768 = 64 rowblocks x 12 splits
    const int rowblk = bid & 63;           // bid%8 = rowblk%8 -> rowblock pinned to one XCD
    const int s12 = bid >> 6;
    const int rowbase = rowblk * 128;
    const int t0 = (s12 * 128) / 12;       // 64-col tile range [t0,t1)
    const int t1 = ((s12 + 1) * 128) / 12;

    const int tid = threadIdx.x;
    const int lane = tid & 63;
    const int wave = tid >> 6;
    const int wr = wave >> 1, wc = wave & 1;   // 2x2: 64 rows x 32 cols per wave
    const int l15 = lane & 15, lhi = lane >> 4;

    // ---- stage A (128 x 256B = 32 KB) across both bufs ----
    {
        const char* src = ebf + ((size_t)(rowbase + wave * 32 + lhi) << 8) + (l15 << 4);
        char* dst = smem + wave * 8192;
        #pragma unroll
        for (int i = 0; i < 8; ++i) glds16(src + i * 1024, dst + i * 1024);
    }
    __syncthreads();
    // ---- hoist A fragments to registers ----
    bf16x8 aF[4][4];   // [rf][ks] = 64 VGPRs
    #pragma unroll
    for (int rf = 0; rf < 4; ++rf) {
        int row = wr * 64 + rf * 16 + l15;
        #pragma unroll
        for (int ks = 0; ks < 4; ++ks)
            aF[rf][ks] = *(const bf16x8*)(smem + row * 256 + ((ks * 64 + lhi * 16) ^ (l15 << 4)));
    }
    __syncthreads();   // all hoists done, bufs free

    // ---- prologue: stage B(t0) into buf0 ----
    {
        const char* src = ebf + ((size_t)(t0 * 64 + wave * 16 + lhi) << 8) + (l15 << 4);
        char* dst = smem + wave * 4096;
        #pragma unroll
        for (int i = 0; i < 4; ++i) glds16(src + i * 1024, dst + i * 1024);
    }
    __syncthreads();   // B(t0) resident

    float se[4][4];
    #pragma unroll
    for (int rf = 0; rf < 4; ++rf)
        #pragma unroll
        for (int reg = 0; reg < 4; ++reg) se[rf][reg] = 0.f;

    int pb = 0;
    for (int t = t0; t < t1; ++t) {
        if (t + 1 < t1) {   // stage next tile first (overlaps compute)
            const char* src = ebf + ((size_t)((t + 1) * 64 + wave * 16 + lhi) << 8) + (l15 << 4);
            char* dst = smem + (pb ^ 1) * 16384 + wave * 4096;
            #pragma unroll
            for (int i = 0; i < 4; ++i) glds16(src + i * 1024, dst + i * 1024);
        }
        const char* cur = smem + pb * 16384;

        f32x4 acc[4][2];
        #pragma unroll
        for (int rf = 0; rf < 4; ++rf)
            #pragma unroll
            for (int cf = 0; cf < 2; ++cf) acc[rf][cf] = (f32x4){0.f, 0.f, 0.f, 0.f};

        #pragma unroll
        for (int ks = 0; ks < 4; ++ks) {
            const int kb = (ks * 64 + lhi * 16) ^ (l15 << 4);
            bf16x8 bF[2];
            #pragma unroll
            for (int cf = 0; cf < 2; ++cf) {
                int col = wc * 32 + cf * 16 + l15;
                bF[cf] = *(const bf16x8*)(cur + col * 256 + kb);
            }
            #pragma unroll
            for (int rf = 0; rf < 4; ++rf)
                #pragma unroll
                for (int cf = 0; cf < 2; ++cf)
                    acc[rf][cf] = __builtin_amdgcn_mfma_f32_16x16x32_bf16(
                        aF[rf][ks], bF[cf], acc[rf][cf], 0, 0, 0);
        }

        // epilogue: acc already = sim * log2e / T (pre-scaled data); one exp2 + add per elem
        unsigned dgu = (unsigned)(t * 64 - rowbase);

#define EPILOGUE(HD)                                                          \
        _Pragma("unroll")                                                     \
        for (int rf = 0; rf < 4; ++rf)                                        \
            _Pragma("unroll")                                                 \
            for (int cf = 0; cf < 2; ++cf)                                    \
                _Pragma("unroll")                                             \
                for (int reg = 0; reg < 4; ++reg) {                           \
                    float e = fast_exp2(acc[rf][cf][reg]);                    \
                    if (HD) {                                                 \
                        int lrow = wr * 64 + rf * 16 + lhi * 4 + reg;         \
                        int lcol = (int)dgu + wc * 32 + cf * 16 + l15;        \
                        e = (lrow == lcol) ? 0.f : e;                         \
                    }                                                         \
                    se[rf][reg] += e;                                         \
                }

        if (dgu < 128u) { EPILOGUE(true) } else { EPILOGUE(false) }
#undef EPILOGUE

        __syncthreads();   // next tile landed + all waves done with cur
        pb ^= 1;
    }

    // ---- reduce over 16 col-lanes, one atomic per row ----
    #pragma unroll
    for (int m = 1; m < 16; m <<= 1)
        #pragma unroll
        for (int rf = 0; rf < 4; ++rf)
            #pragma unroll
            for (int reg = 0; reg < 4; ++reg)
                se[rf][reg] += __shfl_xor(se[rf][reg], m);
    if (l15 == 0) {
        #pragma unroll
        for (int rf = 0; rf < 4; ++rf)
            #pragma unroll
            for (int reg = 0; reg < 4; ++reg) {
                int row = rowbase + wr * 64 + rf * 16 + lhi * 4 + reg;
                atomicAdd(&se_ws[row], se[rf][reg]);
            }
    }
}

// ============ k_rowfinal: per-row analytic pos-sum + combine + write out ============
__global__ __launch_bounds__(256) void k_rowfinal(const float* __restrict__ emb,
                                                  const int* __restrict__ lab,
                                                  char* __restrict__ ws,
                                                  float* __restrict__ out, int N) {
    __shared__ float red[256];
    int* ctrs = (int*)(ws + CTR_OFF);
    const int r = blockIdx.x * 256 + threadIdx.x;
    const int flag64 = ctrs[0];
    float contrib = 0.f;
    if (r < N) {
        int L = flag64 ? lab[2 * r] : lab[r];
        const float* Sr = (const float*)(ws + S_OFF) + L * N_D;
        const float* er = emb + (size_t)r * N_D;
        float dot = 0.f, nrm = 0.f;
        #pragma unroll 8
        for (int k = 0; k < N_D; k += 4) {
            float4 e = *(const float4*)(er + k);
            float4 s4 = *(const float4*)(Sr + k);
            dot += e.x * s4.x + e.y * s4.y + e.z * s4.z + e.w * s4.w;
            nrm += e.x * e.x + e.y * e.y + e.z * e.z + e.w * e.w;
        }
        float pc = ((const float*)(ws + CNT_OFF))[L] - 1.f;
        float sev = ((const float*)(ws + SE_OFF))[r];
        if (pc > 0.f)
            contrib = ((dot - nrm) * TEMP_INV - pc * logf(sev + 1e-9f)) / pc;
    }
    red[threadIdx.x] = contrib;
    __syncthreads();
    for (int s = 128; s > 0; s >>= 1) {
        if (threadIdx.x < s) red[threadIdx.x] += red[threadIdx.x + s];
        __syncthreads();
    }
    if (threadIdx.x == 0) {
        atomicAdd((float*)&ctrs[1], red[0]);
        __threadfence();
        if (atomicAdd(&ctrs[2], 1) == (int)gridDim.x - 1) {
            float fin = atomicAdd((float*)&ctrs[1], 0.0f);   // device-scope read
            out[0] = -fin / (float)N;
        }
    }
}

// ======================= fallback (round-2 proven path) =======================
#define FBI 128
#define FBJ 64
#define FNSPLIT 8

__global__ void fb_prep(const int* __restrict__ lab32, float* __restrict__ ws, int N) {
    int tid = blockIdx.x * blockDim.x + threadIdx.x;
    int total = 3 * N;
    for (int i = tid; i < total; i += gridDim.x * blockDim.x) ws[i] = 0.0f;
    if (blockIdx.x == 0) {
        __shared__ int nz;
        if (threadIdx.x == 0) nz = 0;
        __syncthreads();
        int local = 0;
        int half = N >> 1;
        for (int i = threadIdx.x; i < half; i += blockDim.x)
            if (lab32[2 * i + 1] != 0) local = 1;
        if (local) atomicOr(&nz, 1);
        __syncthreads();
        if (threadIdx.x == 0) ((int*)ws)[3 * N] = (nz == 0) ? 1 : 0;
    }
}

__global__ __launch_bounds__(256) void fb_main(const float* __restrict__ emb,
                                               const int* __restrict__ lab32,
                                               float* __restrict__ ws, int N) {
    __shared__ ushort Ash[FBI * N_D];
    __shared__ ushort Bsh[FBJ * N_D];
    __shared__ int labA[FBI];
    __shared__ int labB[FBJ];

    const int tid  = threadIdx.x;
    const int lane = tid & 63;
    const int wave = tid >> 6;
    const int wr = wave >> 1;
    const int wc = wave & 1;
    const int l15 = lane & 15;
    const int lhi = lane >> 4;
    const int rowbase  = blockIdx.x * FBI;
    const int colsPer  = N / FNSPLIT;
    const int colstart = blockIdx.y * colsPer;
    const int flag64 = ((const int*)ws)[3 * N];

    for (int id = tid; id < FBI * 32; id += 256) {
        int row = id >> 5, k4 = id & 31;
        float4 v = *(const float4*)&emb[(size_t)(rowbase + row) * N_D + (k4 << 2)];
        uint p0 = (uint)f2bf(v.x) | ((uint)f2bf(v.y) << 16);
        uint p1 = (uint)f2bf(v.z) | ((uint)f2bf(v.w) << 16);
        int byte = (row << 8) + (k4 << 3);
        byte ^= (row & 7) << 4;
        *(uint2*)((char*)Ash + byte) = make_uint2(p0, p1);
    }
    if (tid < FBI) {
        int g = rowbase + tid;
        labA[tid] = flag64 ? lab32[2 * g] : lab32[g];
    }
    __syncthreads();

    int labR[4][4];
    const int rowc = rowbase + wr * 64 + lhi * 4;
    #pragma unroll
    for (int rf = 0; rf < 4; ++rf)
        #pragma unroll
        for (int reg = 0; reg < 4; ++reg)
            labR[rf][reg] = labA[wr * 64 + rf * 16 + lhi * 4 + reg];

    float se[4][4], ps[4][4], pc[4][4];
    #pragma unroll
    for (int rf = 0; rf < 4; ++rf)
        #pragma unroll
        for (int reg = 0; reg < 4; ++reg) { se[rf][reg] = 0.f; ps[rf][reg] = 0.f; pc[rf][reg] = 0.f; }

    for (int jt = colstart; jt < colstart + colsPer; jt += FBJ) {
        __syncthreads();
        for (int id = tid; id < FBJ * 32; id += 256) {
            int row = id >> 5, k4 = id & 31;
            float4 v = *(const float4*)&emb[(size_t)(jt + row) * N_D + (k4 << 2)];
            uint p0 = (uint)f2bf(v.x) | ((uint)f2bf(v.y) << 16);
            uint p1 = (uint)f2bf(v.z) | ((uint)f2bf(v.w) << 16);
            int byte = (row << 8) + (k4 << 3);
            byte ^= (row & 7) << 4;
            *(uint2*)((char*)Bsh + byte) = make_uint2(p0, p1);
        }
        if (tid < FBJ) {
            int g = jt + tid;
            labB[tid] = flag64 ? lab32[2 * g] : lab32[g];
        }
        __syncthreads();

        f32x4 zero4 = {0.f, 0.f, 0.f, 0.f};
        f32x4 acc[4][2];
        #pragma unroll
        for (int rf = 0; rf < 4; ++rf)
            #pragma unroll
            for (int cf = 0; cf < 2; ++cf) acc[rf][cf] = zero4;

        const int kbyteBase = lhi * 16;
        #pragma unroll
        for (int ks = 0; ks < 4; ++ks) {
            int kb = ks * 64 + kbyteBase;
            bf16x8 aF[4], bF[2];
            #pragma unroll
            for (int rf = 0; rf < 4; ++rf) {
                int row = wr * 64 + rf * 16 + l15;
                int byte = (row << 8) + kb;
                byte ^= (row & 7) << 4;
                aF[rf] = *(bf16x8*)((char*)Ash + byte);
            }
            #pragma unroll
            for (int cf = 0; cf < 2; ++cf) {
                int col = wc * 32 + cf * 16 + l15;
                int byte = (col << 8) + kb;
                byte ^= (col & 7) << 4;
                bF[cf] = *(bf16x8*)((char*)Bsh + byte);
            }
            #pragma unroll
            for (int rf = 0; rf < 4; ++rf)
                #pragma unroll
                for (int cf = 0; cf < 2; ++cf)
                    acc[rf][cf] = __builtin_amdgcn_mfma_f32_16x16x32_bf16(
                        aF[rf], bF[cf], acc[rf][cf], 0, 0, 0);
        }

        int labC[2], gcol[2];
        #pragma unroll
        for (int cf = 0; cf < 2; ++cf) {
            int col = wc * 32 + cf * 16 + l15;
            labC[cf] = labB[col];
            gcol[cf] = jt + col;
        }
        bool hasdiag = (jt < rowbase + FBI) && (jt + FBJ > rowbase);

#define EPILOGUE(HD)                                                          \
        _Pragma("unroll")                                                     \
        for (int cf = 0; cf < 2; ++cf) {                                      \
            _Pragma("unroll")                                                 \
            for (int rf = 0; rf < 4; ++rf) {                                  \
                _Pragma("unroll")                                             \
                for (int reg = 0; reg < 4; ++reg) {                           \
                    float sim = acc[rf][cf][reg] * TEMP_INV;                  \
                    float e = __expf(sim);                                    \
                    bool pos = (labR[rf][reg] == labC[cf]);                   \
                    if (HD) {                                                 \
                        bool diag = ((rowc + rf * 16 + reg) == gcol[cf]);     \
                        e = diag ? 0.f : e;                                   \
                        pos = pos && !diag;                                   \
                    }                                                         \
                    se[rf][reg] += e;                                         \
                    ps[rf][reg] += pos ? sim : 0.f;                           \
                    pc[rf][reg] += pos ? 1.f : 0.f;                           \
                }                                                             \
            }                                                                 \
        }

        if (hasdiag) { EPILOGUE(true) } else { EPILOGUE(false) }
#undef EPILOGUE
    }

    for (int m = 1; m < 16; m <<= 1) {
        #pragma unroll
        for (int rf = 0; rf < 4; ++rf)
            #pragma unroll
            for (int reg = 0; reg < 4; ++reg) {
                se[rf][reg] += __shfl_xor(se[rf][reg], m);
                ps[rf][reg] += __shfl_xor(ps[rf][reg], m);
                pc[rf][reg] += __shfl_xor(pc[rf][reg], m);
            }
    }
    if (l15 == 0) {
        #pragma unroll
        for (int rf = 0; rf < 4; ++rf)
            #pragma unroll
            for (int reg = 0; reg < 4; ++reg) {
                int row = rowc + rf * 16 + reg;
                atomicAdd(&ws[row],         se[rf][reg]);
                atomicAdd(&ws[N + row],     ps[rf][reg]);
                atomicAdd(&ws[2 * N + row], pc[rf][reg]);
            }
    }
}

__global__ void fb_final(const float* __restrict__ ws, float* __restrict__ out, int N) {
    __shared__ float red[256];
    float local = 0.0f;
    for (int i = threadIdx.x; i < N; i += 256) {
        float sev = ws[i], psv = ws[N + i], pcv = ws[2 * N + i];
        float lp = psv - pcv * logf(sev + 1e-9f);
        float denom = (pcv == 0.0f) ? 1.0f : pcv;
        local += lp / denom;
    }
    red[threadIdx.x] = local;
    __syncthreads();
    for (int s = 128; s > 0; s >>= 1) {
        if (threadIdx.x < s) red[threadIdx.x] += red[threadIdx.x + s];
        __syncthreads();
    }
    if (threadIdx.x == 0) out[0] = -red[0] / (float)N;
}

// ======================= launcher =======================
extern "C" void kernel_launch(void* const* d_in, const int* in_sizes, int n_in,
                              void* d_out, int out_size, void* d_ws, size_t ws_size,
                              hipStream_t stream) {
    const float* emb = (const float*)d_in[0];
    const int* lab = (const int*)d_in[1];
    float* out = (float*)d_out;
    const int N = in_sizes[0] / N_D;

    if (N == 8192 && ws_size >= (size_t)WS_NEEDED) {
        char* ws = (char*)d_ws;
        hipLaunchKernelGGL(k_pre, dim3(613), dim3(256), 0, stream, emb, lab, ws, N);
        hipLaunchKernelGGL(k_main, dim3(768), dim3(256), 0, stream, ws, N);
        hipLaunchKernelGGL(k_rowfinal, dim3(32), dim3(256), 0, stream, emb, lab, ws, out, N);
    } else {
        float* ws = (float*)d_ws;
        hipLaunchKernelGGL(fb_prep, dim3(32), dim3(256), 0, stream, lab, ws, N);
        dim3 grid(N / FBI, FNSPLIT);
        hipLaunchKernelGGL(fb_main, grid, dim3(256), 0, stream, emb, lab, ws, N);
        hipLaunchKernelGGL(fb_final, dim3(1), dim3(256), 0, stream, ws, out, N);
    }
}

// Round 12
// 48.887 us; speedup vs baseline: 2.0845x; 1.0852x over previous
//
#include <hip/hip_runtime.h>
#include <hip/hip_bf16.h>
#include <math.h>

#define N_D 128
#define TEMP_INV 14.285714285714286f
#define EXP2_SCALE 20.60992915555662f   // (1/0.07) * log2(e)
#define SQRT_E2S 4.539816f              // sqrt(EXP2_SCALE); folded into bf16 data

using bf16x8 = __attribute__((ext_vector_type(8))) short;
using f32x4  = __attribute__((ext_vector_type(4))) float;

// ---------------- ws layout (bytes), N=8192 fast path ----------------
#define EBF_OFF   0u          // 8192*128 bf16, PRE-SWIZZLED rows, PRE-SCALED by SQRT_E2S (2 MB)
#define SE_OFF    2097152u    // 8192 f32 row exp-sums (zeroed by k_pre misc block)
#define S_OFF     2129920u    // 100*128 f32 class sums (raw emb)
#define CNT_OFF   2181120u    // 100 f32 class counts
#define CTR_OFF   2181632u    // 256 ints: [0]=flag64 [1]=FIN(f32) [2]=DONE
#define WS_NEEDED 2182656u

__device__ __forceinline__ ushort f2bf(float f) {
    __hip_bfloat16 h = __float2bfloat16(f);
    return *reinterpret_cast<ushort*>(&h);
}

__device__ __forceinline__ float fast_exp2(float x) {
#if __has_builtin(__builtin_amdgcn_exp2f)
    return __builtin_amdgcn_exp2f(x);
#else
    float r; asm("v_exp_f32 %0, %1" : "=v"(r) : "v"(x)); return r;
#endif
}

__device__ __forceinline__ void glds16(const void* src, void* dst) {
    __builtin_amdgcn_global_load_lds(
        (const __attribute__((address_space(1))) unsigned int*)src,
        (__attribute__((address_space(3))) unsigned int*)dst, 16, 0, 0);
}

__device__ int detect_i64(const int* lab, int N) {
    __shared__ int s_any;
    if (threadIdx.x == 0) s_any = 0;
    __syncthreads();
    int any = 0;
    for (int i = threadIdx.x; i < (N >> 1); i += blockDim.x)
        any |= (lab[2 * i + 1] != 0);
    if (__any(any) && (threadIdx.x & 63) == 0) atomicOr(&s_any, 1);
    __syncthreads();
    return s_any ? 0 : 1;   // all odd words zero => int64
}

// ====== k_pre: [0,512) bf16 convert (pre-swizzled, pre-scaled) | [512,612) class sums | 612 misc ======
__global__ __launch_bounds__(256) void k_pre(const float* __restrict__ emb,
                                             const int* __restrict__ lab,
                                             char* __restrict__ ws, int N) {
    __shared__ int list[1024];
    __shared__ int lcnt;
    __shared__ float tmp[128];
    const int blk = blockIdx.x;
    const int tid = threadIdx.x;

    if (blk < 512) {
        // convert: id -> row g, slot s; store orig[g][s ^ (g&15)] at [g][s], scaled
        int id = blk * 256 + tid;            // 0 .. 131071
        int g = id >> 4, s = id & 15;
        int srcslot = s ^ (g & 15);
        const float* src = emb + (size_t)g * N_D + srcslot * 8;
        float4 v0 = *(const float4*)src;
        float4 v1 = *(const float4*)(src + 4);
        uint4 o;
        o.x = (uint)f2bf(v0.x * SQRT_E2S) | ((uint)f2bf(v0.y * SQRT_E2S) << 16);
        o.y = (uint)f2bf(v0.z * SQRT_E2S) | ((uint)f2bf(v0.w * SQRT_E2S) << 16);
        o.z = (uint)f2bf(v1.x * SQRT_E2S) | ((uint)f2bf(v1.y * SQRT_E2S) << 16);
        o.w = (uint)f2bf(v1.z * SQRT_E2S) | ((uint)f2bf(v1.w * SQRT_E2S) << 16);
        ((uint4*)(ws + EBF_OFF))[id] = o;
        return;
    }
    if (blk < 612) {
        // class-sum for class c: one full-N index list, then 8-deep ILP row sums
        int c = blk - 512;
        int flag64 = detect_i64(lab, N);
        if (tid == 0) lcnt = 0;
        __syncthreads();
        for (int i = tid; i < N; i += 256) {
            int L = flag64 ? lab[2 * i] : lab[i];
            if (L == c) list[atomicAdd(&lcnt, 1) & 1023] = i;
        }
        __syncthreads();
        int n = lcnt; if (n > 1024) n = 1024;
        int stream = tid >> 7;      // 0/1
        int d = tid & 127;
        float acc = 0.f;
        int j = stream;
        while (j + 14 < n) {        // 8 independent loads in flight
            float t0 = emb[(size_t)list[j     ] * N_D + d];
            float t1 = emb[(size_t)list[j +  2] * N_D + d];
            float t2 = emb[(size_t)list[j +  4] * N_D + d];
            float t3 = emb[(size_t)list[j +  6] * N_D + d];
            float t4 = emb[(size_t)list[j +  8] * N_D + d];
            float t5 = emb[(size_t)list[j + 10] * N_D + d];
            float t6 = emb[(size_t)list[j + 12] * N_D + d];
            float t7 = emb[(size_t)list[j + 14] * N_D + d];
            acc += ((t0 + t1) + (t2 + t3)) + ((t4 + t5) + (t6 + t7));
            j += 16;
        }
        for (; j < n; j += 2) acc += emb[(size_t)list[j] * N_D + d];
        if (stream == 1) tmp[d] = acc;
        __syncthreads();
        if (stream == 0) {
            ((float*)(ws + S_OFF))[c * N_D + d] = acc + tmp[d];
            if (d == 0) ((float*)(ws + CNT_OFF))[c] = (float)n;
        }
        return;
    }
    // misc block: flag + zero se + zero all counters
    {
        int flag64 = detect_i64(lab, N);
        float* se = (float*)(ws + SE_OFF);
        for (int i = tid; i < N; i += 256) se[i] = 0.f;
        int* ctrs = (int*)(ws + CTR_OFF);
        if (tid < 256) ctrs[tid] = (tid == 0) ? flag64 : 0;
    }
}

// ====== k_main: BJ=128 tiles, 512 blocks (2/CU even), (256,2), no tail ======
__global__ __launch_bounds__(256, 2) void k_main(char* __restrict__ ws, int N) {
    __shared__ __attribute__((aligned(128))) char smem[65536];  // buf0/buf1 32KB each

    const char* ebf = ws + EBF_OFF;
    float* se_ws = (float*)(ws + SE_OFF);

    const int bid = blockIdx.x;            // 512 = 64 rowblocks x 8 splits
    const int rowblk = bid & 63;           // bid%8 = rowblk%8 -> rowblock pinned to one XCD
    const int s8 = bid >> 6;               // 0..7
    const int rowbase = rowblk * 128;
    const int t0 = s8 * 8;                 // 128-col tile range [t0, t0+8)
    const int t1 = t0 + 8;

    const int tid = threadIdx.x;
    const int lane = tid & 63;
    const int wave = tid >> 6;
    const int wr = wave >> 1, wc = wave & 1;   // 2x2: 64 rows x 64 cols per wave
    const int l15 = lane & 15, lhi = lane >> 4;

    // ---- stage A (128 x 256B = 32 KB) into buf0 ----
    {
        const char* src = ebf + ((size_t)(rowbase + wave * 32 + lhi) << 8) + (l15 << 4);
        char* dst = smem + wave * 8192;
        #pragma unroll
        for (int i = 0; i < 8; ++i) glds16(src + i * 1024, dst + i * 1024);
    }
    __syncthreads();
    // ---- hoist A fragments to registers ----
    bf16x8 aF[4][4];   // [rf][ks] = 64 VGPRs
    #pragma unroll
    for (int rf = 0; rf < 4; ++rf) {
        int row = wr * 64 + rf * 16 + l15;
        #pragma unroll
        for (int ks = 0; ks < 4; ++ks)
            aF[rf][ks] = *(const bf16x8*)(smem + row * 256 + ((ks * 64 + lhi * 16) ^ (l15 << 4)));
    }
    __syncthreads();   // hoists done, buf0 free

    // ---- prologue: stage B(t0) into buf0 ----
    {
        const char* src = ebf + ((size_t)(t0 * 128 + wave * 32 + lhi) << 8) + (l15 << 4);
        char* dst = smem + wave * 8192;
        #pragma unroll
        for (int i = 0; i < 8; ++i) glds16(src + i * 1024, dst + i * 1024);
    }
    __syncthreads();   // B(t0) resident

    float se[4][4];
    #pragma unroll
    for (int rf = 0; rf < 4; ++rf)
        #pragma unroll
        for (int reg = 0; reg < 4; ++reg) se[rf][reg] = 0.f;

    int pb = 0;
    for (int t = t0; t < t1; ++t) {
        if (t + 1 < t1) {   // stage next 128-col tile first (overlaps compute)
            const char* src = ebf + ((size_t)((t + 1) * 128 + wave * 32 + lhi) << 8) + (l15 << 4);
            char* dst = smem + (pb ^ 1) * 32768 + wave * 8192;
            #pragma unroll
            for (int i = 0; i < 8; ++i) glds16(src + i * 1024, dst + i * 1024);
        }
        const char* cur = smem + pb * 32768;

        f32x4 acc[4][4];
        #pragma unroll
        for (int rf = 0; rf < 4; ++rf)
            #pragma unroll
            for (int cf = 0; cf < 4; ++cf) acc[rf][cf] = (f32x4){0.f, 0.f, 0.f, 0.f};

        #pragma unroll
        for (int ks = 0; ks < 4; ++ks) {
            const int kb = (ks * 64 + lhi * 16) ^ (l15 << 4);
            bf16x8 bF[4];
            #pragma unroll
            for (int cf = 0; cf < 4; ++cf) {
                int col = wc * 64 + cf * 16 + l15;
                bF[cf] = *(const bf16x8*)(cur + col * 256 + kb);
            }
            #pragma unroll
            for (int rf = 0; rf < 4; ++rf)
                #pragma unroll
                for (int cf = 0; cf < 4; ++cf)
                    acc[rf][cf] = __builtin_amdgcn_mfma_f32_16x16x32_bf16(
                        aF[rf][ks], bF[cf], acc[rf][cf], 0, 0, 0);
        }

        // epilogue: acc already = sim * log2e / T (pre-scaled data); one exp2 + add per elem
        unsigned dgu = (unsigned)(t * 128 - rowbase);

#define EPILOGUE(HD)                                                          \
        _Pragma("unroll")                                                     \
        for (int rf = 0; rf < 4; ++rf)                                        \
            _Pragma("unroll")                                                 \
            for (int cf = 0; cf < 4; ++cf)                                    \
                _Pragma("unroll")                                             \
                for (int reg = 0; reg < 4; ++reg) {                           \
                    float e = fast_exp2(acc[rf][cf][reg]);                    \
                    if (HD) {                                                 \
                        int lrow = wr * 64 + rf * 16 + lhi * 4 + reg;         \
                        int lcol = wc * 64 + cf * 16 + l15;                   \
                        e = (lrow == lcol) ? 0.f : e;                         \
                    }                                                         \
                    se[rf][reg] += e;                                         \
                }

        if (dgu == 0u) { EPILOGUE(true) } else { EPILOGUE(false) }
#undef EPILOGUE

        __syncthreads();   // next tile landed + all waves done with cur
        pb ^= 1;
    }

    // ---- reduce over 16 col-lanes, one atomic per row ----
    #pragma unroll
    for (int m = 1; m < 16; m <<= 1)
        #pragma unroll
        for (int rf = 0; rf < 4; ++rf)
            #pragma unroll
            for (int reg = 0; reg < 4; ++reg)
                se[rf][reg] += __shfl_xor(se[rf][reg], m);
    if (l15 == 0) {
        #pragma unroll
        for (int rf = 0; rf < 4; ++rf)
            #pragma unroll
            for (int reg = 0; reg < 4; ++reg) {
                int row = rowbase + wr * 64 + rf * 16 + lhi * 4 + reg;
                atomicAdd(&se_ws[row], se[rf][reg]);
            }
    }
}

// ============ k_rowfinal: per-row analytic pos-sum + combine + write out ============
__global__ __launch_bounds__(256) void k_rowfinal(const float* __restrict__ emb,
                                                  const int* __restrict__ lab,
                                                  char* __restrict__ ws,
                                                  float* __restrict__ out, int N) {
    __shared__ float red[256];
    int* ctrs = (int*)(ws + CTR_OFF);
    const int r = blockIdx.x * 256 + threadIdx.x;
    const int flag64 = ctrs[0];
    float contrib = 0.f;
    if (r < N) {
        int L = flag64 ? lab[2 * r] : lab[r];
        const float* Sr = (const float*)(ws + S_OFF) + L * N_D;
        const float* er = emb + (size_t)r * N_D;
        float dot = 0.f, nrm = 0.f;
        #pragma unroll 8
        for (int k = 0; k < N_D; k += 4) {
            float4 e = *(const float4*)(er + k);
            float4 s4 = *(const float4*)(Sr + k);
            dot += e.x * s4.x + e.y * s4.y + e.z * s4.z + e.w * s4.w;
            nrm += e.x * e.x + e.y * e.y + e.z * e.z + e.w * e.w;
        }
        float pc = ((const float*)(ws + CNT_OFF))[L] - 1.f;
        float sev = ((const float*)(ws + SE_OFF))[r];
        if (pc > 0.f)
            contrib = ((dot - nrm) * TEMP_INV - pc * logf(sev + 1e-9f)) / pc;
    }
    red[threadIdx.x] = contrib;
    __syncthreads();
    for (int s = 128; s > 0; s >>= 1) {
        if (threadIdx.x < s) red[threadIdx.x] += red[threadIdx.x + s];
        __syncthreads();
    }
    if (threadIdx.x == 0) {
        atomicAdd((float*)&ctrs[1], red[0]);
        __threadfence();
        if (atomicAdd(&ctrs[2], 1) == (int)gridDim.x - 1) {
            float fin = atomicAdd((float*)&ctrs[1], 0.0f);   // device-scope read
            out[0] = -fin / (float)N;
        }
    }
}

// ======================= fallback (round-2 proven path) =======================
#define FBI 128
#define FBJ 64
#define FNSPLIT 8

__global__ void fb_prep(const int* __restrict__ lab32, float* __restrict__ ws, int N) {
    int tid = blockIdx.x * blockDim.x + threadIdx.x;
    int total = 3 * N;
    for (int i = tid; i < total; i += gridDim.x * blockDim.x) ws[i] = 0.0f;
    if (blockIdx.x == 0) {
        __shared__ int nz;
        if (threadIdx.x == 0) nz = 0;
        __syncthreads();
        int local = 0;
        int half = N >> 1;
        for (int i = threadIdx.x; i < half; i += blockDim.x)
            if (lab32[2 * i + 1] != 0) local = 1;
        if (local) atomicOr(&nz, 1);
        __syncthreads();
        if (threadIdx.x == 0) ((int*)ws)[3 * N] = (nz == 0) ? 1 : 0;
    }
}

__global__ __launch_bounds__(256) void fb_main(const float* __restrict__ emb,
                                               const int* __restrict__ lab32,
                                               float* __restrict__ ws, int N) {
    __shared__ ushort Ash[FBI * N_D];
    __shared__ ushort Bsh[FBJ * N_D];
    __shared__ int labA[FBI];
    __shared__ int labB[FBJ];

    const int tid  = threadIdx.x;
    const int lane = tid & 63;
    const int wave = tid >> 6;
    const int wr = wave >> 1;
    const int wc = wave & 1;
    const int l15 = lane & 15;
    const int lhi = lane >> 4;
    const int rowbase  = blockIdx.x * FBI;
    const int colsPer  = N / FNSPLIT;
    const int colstart = blockIdx.y * colsPer;
    const int flag64 = ((const int*)ws)[3 * N];

    for (int id = tid; id < FBI * 32; id += 256) {
        int row = id >> 5, k4 = id & 31;
        float4 v = *(const float4*)&emb[(size_t)(rowbase + row) * N_D + (k4 << 2)];
        uint p0 = (uint)f2bf(v.x) | ((uint)f2bf(v.y) << 16);
        uint p1 = (uint)f2bf(v.z) | ((uint)f2bf(v.w) << 16);
        int byte = (row << 8) + (k4 << 3);
        byte ^= (row & 7) << 4;
        *(uint2*)((char*)Ash + byte) = make_uint2(p0, p1);
    }
    if (tid < FBI) {
        int g = rowbase + tid;
        labA[tid] = flag64 ? lab32[2 * g] : lab32[g];
    }
    __syncthreads();

    int labR[4][4];
    const int rowc = rowbase + wr * 64 + lhi * 4;
    #pragma unroll
    for (int rf = 0; rf < 4; ++rf)
        #pragma unroll
        for (int reg = 0; reg < 4; ++reg)
            labR[rf][reg] = labA[wr * 64 + rf * 16 + lhi * 4 + reg];

    float se[4][4], ps[4][4], pc[4][4];
    #pragma unroll
    for (int rf = 0; rf < 4; ++rf)
        #pragma unroll
        for (int reg = 0; reg < 4; ++reg) { se[rf][reg] = 0.f; ps[rf][reg] = 0.f; pc[rf][reg] = 0.f; }

    for (int jt = colstart; jt < colstart + colsPer; jt += FBJ) {
        __syncthreads();
        for (int id = tid; id < FBJ * 32; id += 256) {
            int row = id >> 5, k4 = id & 31;
            float4 v = *(const float4*)&emb[(size_t)(jt + row) * N_D + (k4 << 2)];
            uint p0 = (uint)f2bf(v.x) | ((uint)f2bf(v.y) << 16);
            uint p1 = (uint)f2bf(v.z) | ((uint)f2bf(v.w) << 16);
            int byte = (row << 8) + (k4 << 3);
            byte ^= (row & 7) << 4;
            *(uint2*)((char*)Bsh + byte) = make_uint2(p0, p1);
        }
        if (tid < FBJ) {
            int g = jt + tid;
            labB[tid] = flag64 ? lab32[2 * g] : lab32[g];
        }
        __syncthreads();

        f32x4 zero4 = {0.f, 0.f, 0.f, 0.f};
        f32x4 acc[4][2];
        #pragma unroll
        for (int rf = 0; rf < 4; ++rf)
            #pragma unroll
            for (int cf = 0; cf < 2; ++cf) acc[rf][cf] = zero4;

        const int kbyteBase = lhi * 16;
        #pragma unroll
        for (int ks = 0; ks < 4; ++ks) {
            int kb = ks * 64 + kbyteBase;
            bf16x8 aF[4], bF[2];
            #pragma unroll
            for (int rf = 0; rf < 4; ++rf) {
                int row = wr * 64 + rf * 16 + l15;
                int byte = (row << 8) + kb;
                byte ^= (row & 7) << 4;
                aF[rf] = *(bf16x8*)((char*)Ash + byte);
            }
            #pragma unroll
            for (int cf = 0; cf < 2; ++cf) {
                int col = wc * 32 + cf * 16 + l15;
                int byte = (col << 8) + kb;
                byte ^= (col & 7) << 4;
                bF[cf] = *(bf16x8*)((char*)Bsh + byte);
            }
            #pragma unroll
            for (int rf = 0; rf < 4; ++rf)
                #pragma unroll
                for (int cf = 0; cf < 2; ++cf)
                    acc[rf][cf] = __builtin_amdgcn_mfma_f32_16x16x32_bf16(
                        aF[rf], bF[cf], acc[rf][cf], 0, 0, 0);
        }

        int labC[2], gcol[2];
        #pragma unroll
        for (int cf = 0; cf < 2; ++cf) {
            int col = wc * 32 + cf * 16 + l15;
            labC[cf] = labB[col];
            gcol[cf] = jt + col;
        }
        bool hasdiag = (jt < rowbase + FBI) && (jt + FBJ > rowbase);

#define EPILOGUE(HD)                                                          \
        _Pragma("unroll")                                                     \
        for (int cf = 0; cf < 2; ++cf) {                                      \
            _Pragma("unroll")                                                 \
            for (int rf = 0; rf < 4; ++rf) {                                  \
                _Pragma("unroll")                                             \
                for (int reg = 0; reg < 4; ++reg) {                           \
                    float sim = acc[rf][cf][reg] * TEMP_INV;                  \
                    float e = __expf(sim);                                    \
                    bool pos = (labR[rf][reg] == labC[cf]);                   \
                    if (HD) {                                                 \
                        bool diag = ((rowc + rf * 16 + reg) == gcol[cf]);     \
                        e = diag ? 0.f : e;                                   \
                        pos = pos && !diag;                                   \
                    }                                                         \
                    se[rf][reg] += e;                                         \
                    ps[rf][reg] += pos ? sim : 0.f;                           \
                    pc[rf][reg] += pos ? 1.f : 0.f;                           \
                }                                                             \
            }                                                                 \
        }

        if (hasdiag) { EPILOGUE(true) } else { EPILOGUE(false) }
#undef EPILOGUE
    }

    for (int m = 1; m < 16; m <<= 1) {
        #pragma unroll
        for (int rf = 0; rf < 4; ++rf)
            #pragma unroll
            for (int reg = 0; reg < 4; ++reg) {
                se[rf][reg] += __shfl_xor(se[rf][reg], m);
                ps[rf][reg] += __shfl_xor(ps[rf][reg], m);
                pc[rf][reg] += __shfl_xor(pc[rf][reg], m);
            }
    }
    if (l15 == 0) {
        #pragma unroll
        for (int rf = 0; rf < 4; ++rf)
            #pragma unroll
            for (int reg = 0; reg < 4; ++reg) {
                int row = rowc + rf * 16 + reg;
                atomicAdd(&ws[row],         se[rf][reg]);
                atomicAdd(&ws[N + row],     ps[rf][reg]);
                atomicAdd(&ws[2 * N + row], pc[rf][reg]);
            }
    }
}

__global__ void fb_final(const float* __restrict__ ws, float* __restrict__ out, int N) {
    __shared__ float red[256];
    float local = 0.0f;
    for (int i = threadIdx.x; i < N; i += 256) {
        float sev = ws[i], psv = ws[N + i], pcv = ws[2 * N + i];
        float lp = psv - pcv * logf(sev + 1e-9f);
        float denom = (pcv == 0.0f) ? 1.0f : pcv;
        local += lp / denom;
    }
    red[threadIdx.x] = local;
    __syncthreads();
    for (int s = 128; s > 0; s >>= 1) {
        if (threadIdx.x < s) red[threadIdx.x] += red[threadIdx.x + s];
        __syncthreads();
    }
    if (threadIdx.x == 0) out[0] = -red[0] / (float)N;
}

// ======================= launcher =======================
extern "C" void kernel_launch(void* const* d_in, const int* in_sizes, int n_in,
                              void* d_out, int out_size, void* d_ws, size_t ws_size,
                              hipStream_t stream) {
    const float* emb = (const float*)d_in[0];
    const int* lab = (const int*)d_in[1];
    float* out = (float*)d_out;
    const int N = in_sizes[0] / N_D;

    if (N == 8192 && ws_size >= (size_t)WS_NEEDED) {
        char* ws = (char*)d_ws;
        hipLaunchKernelGGL(k_pre, dim3(613), dim3(256), 0, stream, emb, lab, ws, N);
        hipLaunchKernelGGL(k_main, dim3(512), dim3(256), 0, stream, ws, N);
        hipLaunchKernelGGL(k_rowfinal, dim3(32), dim3(256), 0, stream, emb, lab, ws, out, N);
    } else {
        float* ws = (float*)d_ws;
        hipLaunchKernelGGL(fb_prep, dim3(32), dim3(256), 0, stream, lab, ws, N);
        dim3 grid(N / FBI, FNSPLIT);
        hipLaunchKernelGGL(fb_main, grid, dim3(256), 0, stream, emb, lab, ws, N);
        hipLaunchKernelGGL(fb_final, dim3(1), dim3(256), 0, stream, ws, out, N);
    }
}

// Round 13
// 48.608 us; speedup vs baseline: 2.0965x; 1.0057x over previous
//
#include <hip/hip_runtime.h>
#include <hip/hip_bf16.h>
#include <math.h>

#define N_D 128
#define TEMP_INV 14.285714285714286f
#define EXP2_SCALE 20.60992915555662f   // (1/0.07) * log2(e)
#define SQRT_E2S 4.539816f              // sqrt(EXP2_SCALE); folded into bf16 data

using bf16x8 = __attribute__((ext_vector_type(8))) short;
using f32x4  = __attribute__((ext_vector_type(4))) float;

// ---------------- ws layout (bytes), N=8192 fast path ----------------
#define EBF_OFF   0u          // 8192*128 bf16, PRE-SWIZZLED rows, PRE-SCALED by SQRT_E2S (2 MB)
#define SE_OFF    2097152u    // 8192 f32 row exp-sums (zeroed by k_pre misc block)
#define S_OFF     2129920u    // 100*128 f32 class sums (raw emb)
#define CNT_OFF   2181120u    // 100 f32 class counts
#define CTR_OFF   2181632u    // 256 ints: [0]=flag64 [1]=FIN(f32) [2]=DONE
#define WS_NEEDED 2182656u

__device__ __forceinline__ ushort f2bf(float f) {
    __hip_bfloat16 h = __float2bfloat16(f);
    return *reinterpret_cast<ushort*>(&h);
}

__device__ __forceinline__ float fast_exp2(float x) {
#if __has_builtin(__builtin_amdgcn_exp2f)
    return __builtin_amdgcn_exp2f(x);
#else
    float r; asm("v_exp_f32 %0, %1" : "=v"(r) : "v"(x)); return r;
#endif
}

__device__ __forceinline__ void glds16(const void* src, void* dst) {
    __builtin_amdgcn_global_load_lds(
        (const __attribute__((address_space(1))) unsigned int*)src,
        (__attribute__((address_space(3))) unsigned int*)dst, 16, 0, 0);
}

__device__ int detect_i64(const int* lab, int N) {
    __shared__ int s_any;
    if (threadIdx.x == 0) s_any = 0;
    __syncthreads();
    int any = 0;
    for (int i = threadIdx.x; i < (N >> 1); i += blockDim.x)
        any |= (lab[2 * i + 1] != 0);
    if (__any(any) && (threadIdx.x & 63) == 0) atomicOr(&s_any, 1);
    __syncthreads();
    return s_any ? 0 : 1;   // all odd words zero => int64
}

// ====== k_pre: [0,512) bf16 convert (pre-swizzled, pre-scaled) | [512,612) class sums | 612 misc ======
__global__ __launch_bounds__(256) void k_pre(const float* __restrict__ emb,
                                             const int* __restrict__ lab,
                                             char* __restrict__ ws, int N) {
    __shared__ int list[1024];
    __shared__ int lcnt;
    __shared__ float tmp[128];
    const int blk = blockIdx.x;
    const int tid = threadIdx.x;

    if (blk < 512) {
        // convert: id -> row g, slot s; store orig[g][s ^ (g&15)] at [g][s], scaled
        int id = blk * 256 + tid;            // 0 .. 131071
        int g = id >> 4, s = id & 15;
        int srcslot = s ^ (g & 15);
        const float* src = emb + (size_t)g * N_D + srcslot * 8;
        float4 v0 = *(const float4*)src;
        float4 v1 = *(const float4*)(src + 4);
        uint4 o;
        o.x = (uint)f2bf(v0.x * SQRT_E2S) | ((uint)f2bf(v0.y * SQRT_E2S) << 16);
        o.y = (uint)f2bf(v0.z * SQRT_E2S) | ((uint)f2bf(v0.w * SQRT_E2S) << 16);
        o.z = (uint)f2bf(v1.x * SQRT_E2S) | ((uint)f2bf(v1.y * SQRT_E2S) << 16);
        o.w = (uint)f2bf(v1.z * SQRT_E2S) | ((uint)f2bf(v1.w * SQRT_E2S) << 16);
        ((uint4*)(ws + EBF_OFF))[id] = o;
        return;
    }
    if (blk < 612) {
        // class-sum for class c: one full-N index list, then 8-deep ILP row sums
        int c = blk - 512;
        int flag64 = detect_i64(lab, N);
        if (tid == 0) lcnt = 0;
        __syncthreads();
        for (int i = tid; i < N; i += 256) {
            int L = flag64 ? lab[2 * i] : lab[i];
            if (L == c) list[atomicAdd(&lcnt, 1) & 1023] = i;
        }
        __syncthreads();
        int n = lcnt; if (n > 1024) n = 1024;
        int stream = tid >> 7;      // 0/1
        int d = tid & 127;
        float acc = 0.f;
        int j = stream;
        while (j + 14 < n) {        // 8 independent loads in flight
            float t0 = emb[(size_t)list[j     ] * N_D + d];
            float t1 = emb[(size_t)list[j +  2] * N_D + d];
            float t2 = emb[(size_t)list[j +  4] * N_D + d];
            float t3 = emb[(size_t)list[j +  6] * N_D + d];
            float t4 = emb[(size_t)list[j +  8] * N_D + d];
            float t5 = emb[(size_t)list[j + 10] * N_D + d];
            float t6 = emb[(size_t)list[j + 12] * N_D + d];
            float t7 = emb[(size_t)list[j + 14] * N_D + d];
            acc += ((t0 + t1) + (t2 + t3)) + ((t4 + t5) + (t6 + t7));
            j += 16;
        }
        for (; j < n; j += 2) acc += emb[(size_t)list[j] * N_D + d];
        if (stream == 1) tmp[d] = acc;
        __syncthreads();
        if (stream == 0) {
            ((float*)(ws + S_OFF))[c * N_D + d] = acc + tmp[d];
            if (d == 0) ((float*)(ws + CNT_OFF))[c] = (float)n;
        }
        return;
    }
    // misc block: flag + zero se + zero all counters
    {
        int flag64 = detect_i64(lab, N);
        float* se = (float*)(ws + SE_OFF);
        for (int i = tid; i < N; i += 256) se[i] = 0.f;
        int* ctrs = (int*)(ws + CTR_OFF);
        if (tid < 256) ctrs[tid] = (tid == 0) ? flag64 : 0;
    }
}

// ====== k_main: BJ=128, 512 blocks, (256,2); T4 counted-vmcnt loop (no in-loop drain) ======
__global__ __launch_bounds__(256, 2) void k_main(char* __restrict__ ws, int N) {
    __shared__ __attribute__((aligned(128))) char smem[65536];  // buf0/buf1 32KB each

    const char* ebf = ws + EBF_OFF;
    float* se_ws = (float*)(ws + SE_OFF);

    const int bid = blockIdx.x;            // 512 = 64 rowblocks x 8 splits
    const int rowblk = bid & 63;           // bid%8 = rowblk%8 -> rowblock pinned to one XCD
    const int s8 = bid >> 6;               // 0..7
    const int rowbase = rowblk * 128;
    const int t0 = s8 * 8;                 // 128-col tile range [t0, t0+8)
    const int t1 = t0 + 8;

    const int tid = threadIdx.x;
    const int lane = tid & 63;
    const int wave = tid >> 6;
    const int wr = wave >> 1, wc = wave & 1;   // 2x2: 64 rows x 64 cols per wave
    const int l15 = lane & 15, lhi = lane >> 4;

    // ---- stage A (128 x 256B = 32 KB) into buf0 ----
    {
        const char* src = ebf + ((size_t)(rowbase + wave * 32 + lhi) << 8) + (l15 << 4);
        char* dst = smem + wave * 8192;
        #pragma unroll
        for (int i = 0; i < 8; ++i) glds16(src + i * 1024, dst + i * 1024);
    }
    __syncthreads();
    // ---- hoist A fragments to registers ----
    bf16x8 aF[4][4];   // [rf][ks] = 64 VGPRs
    #pragma unroll
    for (int rf = 0; rf < 4; ++rf) {
        int row = wr * 64 + rf * 16 + l15;
        #pragma unroll
        for (int ks = 0; ks < 4; ++ks)
            aF[rf][ks] = *(const bf16x8*)(smem + row * 256 + ((ks * 64 + lhi * 16) ^ (l15 << 4)));
    }
    __syncthreads();   // hoists done, buf0 free

    // ---- prologue: issue B(t0) stage into buf0, NO wait (loop will count it) ----
    {
        const char* src = ebf + ((size_t)(t0 * 128 + wave * 32 + lhi) << 8) + (l15 << 4);
        char* dst = smem + wave * 8192;
        #pragma unroll
        for (int i = 0; i < 8; ++i) glds16(src + i * 1024, dst + i * 1024);
    }

    float se[4][4];
    #pragma unroll
    for (int rf = 0; rf < 4; ++rf)
        #pragma unroll
        for (int reg = 0; reg < 4; ++reg) se[rf][reg] = 0.f;

    int pb = 0;
    for (int t = t0; t < t1; ++t) {
        // barrier 1: all waves done computing t-1 -> buf[pb^1] is reusable
        __builtin_amdgcn_s_barrier();
        if (t + 1 < t1) {
            // stage next tile into the buffer just freed; keep its loads IN FLIGHT
            const char* src = ebf + ((size_t)((t + 1) * 128 + wave * 32 + lhi) << 8) + (l15 << 4);
            char* dst = smem + (pb ^ 1) * 32768 + wave * 8192;
            #pragma unroll
            for (int i = 0; i < 8; ++i) glds16(src + i * 1024, dst + i * 1024);
            // wait only for B(t)'s 8 loads (issued last iter); t+1's 8 remain outstanding
            asm volatile("s_waitcnt vmcnt(8)" ::: "memory");
        } else {
            asm volatile("s_waitcnt vmcnt(0)" ::: "memory");
        }
        // barrier 2: every wave's B(t) loads have landed -> tile visible to all
        __builtin_amdgcn_s_barrier();

        const char* cur = smem + pb * 32768;

        f32x4 acc[4][4];
        #pragma unroll
        for (int rf = 0; rf < 4; ++rf)
            #pragma unroll
            for (int cf = 0; cf < 4; ++cf) acc[rf][cf] = (f32x4){0.f, 0.f, 0.f, 0.f};

        #pragma unroll
        for (int ks = 0; ks < 4; ++ks) {
            const int kb = (ks * 64 + lhi * 16) ^ (l15 << 4);
            bf16x8 bF[4];
            #pragma unroll
            for (int cf = 0; cf < 4; ++cf) {
                int col = wc * 64 + cf * 16 + l15;
                bF[cf] = *(const bf16x8*)(cur + col * 256 + kb);
            }
            #pragma unroll
            for (int rf = 0; rf < 4; ++rf)
                #pragma unroll
                for (int cf = 0; cf < 4; ++cf)
                    acc[rf][cf] = __builtin_amdgcn_mfma_f32_16x16x32_bf16(
                        aF[rf][ks], bF[cf], acc[rf][cf], 0, 0, 0);
        }

        // epilogue: acc already = sim * log2e / T (pre-scaled data); one exp2 + add per elem
        unsigned dgu = (unsigned)(t * 128 - rowbase);

#define EPILOGUE(HD)                                                          \
        _Pragma("unroll")                                                     \
        for (int rf = 0; rf < 4; ++rf)                                        \
            _Pragma("unroll")                                                 \
            for (int cf = 0; cf < 4; ++cf)                                    \
                _Pragma("unroll")                                             \
                for (int reg = 0; reg < 4; ++reg) {                           \
                    float e = fast_exp2(acc[rf][cf][reg]);                    \
                    if (HD) {                                                 \
                        int lrow = wr * 64 + rf * 16 + lhi * 4 + reg;         \
                        int lcol = wc * 64 + cf * 16 + l15;                   \
                        e = (lrow == lcol) ? 0.f : e;                         \
                    }                                                         \
                    se[rf][reg] += e;                                         \
                }

        if (dgu == 0u) { EPILOGUE(true) } else { EPILOGUE(false) }
#undef EPILOGUE

        pb ^= 1;
    }

    // ---- reduce over 16 col-lanes, one atomic per row ----
    #pragma unroll
    for (int m = 1; m < 16; m <<= 1)
        #pragma unroll
        for (int rf = 0; rf < 4; ++rf)
            #pragma unroll
            for (int reg = 0; reg < 4; ++reg)
                se[rf][reg] += __shfl_xor(se[rf][reg], m);
    if (l15 == 0) {
        #pragma unroll
        for (int rf = 0; rf < 4; ++rf)
            #pragma unroll
            for (int reg = 0; reg < 4; ++reg) {
                int row = rowbase + wr * 64 + rf * 16 + lhi * 4 + reg;
                atomicAdd(&se_ws[row], se[rf][reg]);
            }
    }
}

// ============ k_rowfinal: per-row analytic pos-sum + combine + write out ============
__global__ __launch_bounds__(256) void k_rowfinal(const float* __restrict__ emb,
                                                  const int* __restrict__ lab,
                                                  char* __restrict__ ws,
                                                  float* __restrict__ out, int N) {
    __shared__ float red[256];
    int* ctrs = (int*)(ws + CTR_OFF);
    const int r = blockIdx.x * 256 + threadIdx.x;
    const int flag64 = ctrs[0];
    float contrib = 0.f;
    if (r < N) {
        int L = flag64 ? lab[2 * r] : lab[r];
        const float* Sr = (const float*)(ws + S_OFF) + L * N_D;
        const float* er = emb + (size_t)r * N_D;
        float dot = 0.f, nrm = 0.f;
        #pragma unroll 8
        for (int k = 0; k < N_D; k += 4) {
            float4 e = *(const float4*)(er + k);
            float4 s4 = *(const float4*)(Sr + k);
            dot += e.x * s4.x + e.y * s4.y + e.z * s4.z + e.w * s4.w;
            nrm += e.x * e.x + e.y * e.y + e.z * e.z + e.w * e.w;
        }
        float pc = ((const float*)(ws + CNT_OFF))[L] - 1.f;
        float sev = ((const float*)(ws + SE_OFF))[r];
        if (pc > 0.f)
            contrib = ((dot - nrm) * TEMP_INV - pc * logf(sev + 1e-9f)) / pc;
    }
    red[threadIdx.x] = contrib;
    __syncthreads();
    for (int s = 128; s > 0; s >>= 1) {
        if (threadIdx.x < s) red[threadIdx.x] += red[threadIdx.x + s];
        __syncthreads();
    }
    if (threadIdx.x == 0) {
        atomicAdd((float*)&ctrs[1], red[0]);
        __threadfence();
        if (atomicAdd(&ctrs[2], 1) == (int)gridDim.x - 1) {
            float fin = atomicAdd((float*)&ctrs[1], 0.0f);   // device-scope read
            out[0] = -fin / (float)N;
        }
    }
}

// ======================= fallback (round-2 proven path) =======================
#define FBI 128
#define FBJ 64
#define FNSPLIT 8

__global__ void fb_prep(const int* __restrict__ lab32, float* __restrict__ ws, int N) {
    int tid = blockIdx.x * blockDim.x + threadIdx.x;
    int total = 3 * N;
    for (int i = tid; i < total; i += gridDim.x * blockDim.x) ws[i] = 0.0f;
    if (blockIdx.x == 0) {
        __shared__ int nz;
        if (threadIdx.x == 0) nz = 0;
        __syncthreads();
        int local = 0;
        int half = N >> 1;
        for (int i = threadIdx.x; i < half; i += blockDim.x)
            if (lab32[2 * i + 1] != 0) local = 1;
        if (local) atomicOr(&nz, 1);
        __syncthreads();
        if (threadIdx.x == 0) ((int*)ws)[3 * N] = (nz == 0) ? 1 : 0;
    }
}

__global__ __launch_bounds__(256) void fb_main(const float* __restrict__ emb,
                                               const int* __restrict__ lab32,
                                               float* __restrict__ ws, int N) {
    __shared__ ushort Ash[FBI * N_D];
    __shared__ ushort Bsh[FBJ * N_D];
    __shared__ int labA[FBI];
    __shared__ int labB[FBJ];

    const int tid  = threadIdx.x;
    const int lane = tid & 63;
    const int wave = tid >> 6;
    const int wr = wave >> 1;
    const int wc = wave & 1;
    const int l15 = lane & 15;
    const int lhi = lane >> 4;
    const int rowbase  = blockIdx.x * FBI;
    const int colsPer  = N / FNSPLIT;
    const int colstart = blockIdx.y * colsPer;
    const int flag64 = ((const int*)ws)[3 * N];

    for (int id = tid; id < FBI * 32; id += 256) {
        int row = id >> 5, k4 = id & 31;
        float4 v = *(const float4*)&emb[(size_t)(rowbase + row) * N_D + (k4 << 2)];
        uint p0 = (uint)f2bf(v.x) | ((uint)f2bf(v.y) << 16);
        uint p1 = (uint)f2bf(v.z) | ((uint)f2bf(v.w) << 16);
        int byte = (row << 8) + (k4 << 3);
        byte ^= (row & 7) << 4;
        *(uint2*)((char*)Ash + byte) = make_uint2(p0, p1);
    }
    if (tid < FBI) {
        int g = rowbase + tid;
        labA[tid] = flag64 ? lab32[2 * g] : lab32[g];
    }
    __syncthreads();

    int labR[4][4];
    const int rowc = rowbase + wr * 64 + lhi * 4;
    #pragma unroll
    for (int rf = 0; rf < 4; ++rf)
        #pragma unroll
        for (int reg = 0; reg < 4; ++reg)
            labR[rf][reg] = labA[wr * 64 + rf * 16 + lhi * 4 + reg];

    float se[4][4], ps[4][4], pc[4][4];
    #pragma unroll
    for (int rf = 0; rf < 4; ++rf)
        #pragma unroll
        for (int reg = 0; reg < 4; ++reg) { se[rf][reg] = 0.f; ps[rf][reg] = 0.f; pc[rf][reg] = 0.f; }

    for (int jt = colstart; jt < colstart + colsPer; jt += FBJ) {
        __syncthreads();
        for (int id = tid; id < FBJ * 32; id += 256) {
            int row = id >> 5, k4 = id & 31;
            float4 v = *(const float4*)&emb[(size_t)(jt + row) * N_D + (k4 << 2)];
            uint p0 = (uint)f2bf(v.x) | ((uint)f2bf(v.y) << 16);
            uint p1 = (uint)f2bf(v.z) | ((uint)f2bf(v.w) << 16);
            int byte = (row << 8) + (k4 << 3);
            byte ^= (row & 7) << 4;
            *(uint2*)((char*)Bsh + byte) = make_uint2(p0, p1);
        }
        if (tid < FBJ) {
            int g = jt + tid;
            labB[tid] = flag64 ? lab32[2 * g] : lab32[g];
        }
        __syncthreads();

        f32x4 zero4 = {0.f, 0.f, 0.f, 0.f};
        f32x4 acc[4][2];
        #pragma unroll
        for (int rf = 0; rf < 4; ++rf)
            #pragma unroll
            for (int cf = 0; cf < 2; ++cf) acc[rf][cf] = zero4;

        const int kbyteBase = lhi * 16;
        #pragma unroll
        for (int ks = 0; ks < 4; ++ks) {
            int kb = ks * 64 + kbyteBase;
            bf16x8 aF[4], bF[2];
            #pragma unroll
            for (int rf = 0; rf < 4; ++rf) {
                int row = wr * 64 + rf * 16 + l15;
                int byte = (row << 8) + kb;
                byte ^= (row & 7) << 4;
                aF[rf] = *(bf16x8*)((char*)Ash + byte);
            }
            #pragma unroll
            for (int cf = 0; cf < 2; ++cf) {
                int col = wc * 32 + cf * 16 + l15;
                int byte = (col << 8) + kb;
                byte ^= (col & 7) << 4;
                bF[cf] = *(bf16x8*)((char*)Bsh + byte);
            }
            #pragma unroll
            for (int rf = 0; rf < 4; ++rf)
                #pragma unroll
                for (int cf = 0; cf < 2; ++cf)
                    acc[rf][cf] = __builtin_amdgcn_mfma_f32_16x16x32_bf16(
                        aF[rf], bF[cf], acc[rf][cf], 0, 0, 0);
        }

        int labC[2], gcol[2];
        #pragma unroll
        for (int cf = 0; cf < 2; ++cf) {
            int col = wc * 32 + cf * 16 + l15;
            labC[cf] = labB[col];
            gcol[cf] = jt + col;
        }
        bool hasdiag = (jt < rowbase + FBI) && (jt + FBJ > rowbase);

#define EPILOGUE(HD)                                                          \
        _Pragma("unroll")                                                     \
        for (int cf = 0; cf < 2; ++cf) {                                      \
            _Pragma("unroll")                                                 \
            for (int rf = 0; rf < 4; ++rf) {                                  \
                _Pragma("unroll")                                             \
                for (int reg = 0; reg < 4; ++reg) {                           \
                    float sim = acc[rf][cf][reg] * TEMP_INV;                  \
                    float e = __expf(sim);                                    \
                    bool pos = (labR[rf][reg] == labC[cf]);                   \
                    if (HD) {                                                 \
                        bool diag = ((rowc + rf * 16 + reg) == gcol[cf]);     \
                        e = diag ? 0.f : e;                                   \
                        pos = pos && !diag;                                   \
                    }                                                         \
                    se[rf][reg] += e;                                         \
                    ps[rf][reg] += pos ? sim : 0.f;                           \
                    pc[rf][reg] += pos ? 1.f : 0.f;                           \
                }                                                             \
            }                                                                 \
        }

        if (hasdiag) { EPILOGUE(true) } else { EPILOGUE(false) }
#undef EPILOGUE
    }

    for (int m = 1; m < 16; m <<= 1) {
        #pragma unroll
        for (int rf = 0; rf < 4; ++rf)
            #pragma unroll
            for (int reg = 0; reg < 4; ++reg) {
                se[rf][reg] += __shfl_xor(se[rf][reg], m);
                ps[rf][reg] += __shfl_xor(ps[rf][reg], m);
                pc[rf][reg] += __shfl_xor(pc[rf][reg], m);
            }
    }
    if (l15 == 0) {
        #pragma unroll
        for (int rf = 0; rf < 4; ++rf)
            #pragma unroll
            for (int reg = 0; reg < 4; ++reg) {
                int row = rowc + rf * 16 + reg;
                atomicAdd(&ws[row],         se[rf][reg]);
                atomicAdd(&ws[N + row],     ps[rf][reg]);
                atomicAdd(&ws[2 * N + row], pc[rf][reg]);
            }
    }
}

__global__ void fb_final(const float* __restrict__ ws, float* __restrict__ out, int N) {
    __shared__ float red[256];
    float local = 0.0f;
    for (int i = threadIdx.x; i < N; i += 256) {
        float sev = ws[i], psv = ws[N + i], pcv = ws[2 * N + i];
        float lp = psv - pcv * logf(sev + 1e-9f);
        float denom = (pcv == 0.0f) ? 1.0f : pcv;
        local += lp / denom;
    }
    red[threadIdx.x] = local;
    __syncthreads();
    for (int s = 128; s > 0; s >>= 1) {
        if (threadIdx.x < s) red[threadIdx.x] += red[threadIdx.x + s];
        __syncthreads();
    }
    if (threadIdx.x == 0) out[0] = -red[0] / (float)N;
}

// ======================= launcher =======================
extern "C" void kernel_launch(void* const* d_in, const int* in_sizes, int n_in,
                              void* d_out, int out_size, void* d_ws, size_t ws_size,
                              hipStream_t stream) {
    const float* emb = (const float*)d_in[0];
    const int* lab = (const int*)d_in[1];
    float* out = (float*)d_out;
    const int N = in_sizes[0] / N_D;

    if (N == 8192 && ws_size >= (size_t)WS_NEEDED) {
        char* ws = (char*)d_ws;
        hipLaunchKernelGGL(k_pre, dim3(613), dim3(256), 0, stream, emb, lab, ws, N);
        hipLaunchKernelGGL(k_main, dim3(512), dim3(256), 0, stream, ws, N);
        hipLaunchKernelGGL(k_rowfinal, dim3(32), dim3(256), 0, stream, emb, lab, ws, out, N);
    } else {
        float* ws = (float*)d_ws;
        hipLaunchKernelGGL(fb_prep, dim3(32), dim3(256), 0, stream, lab, ws, N);
        dim3 grid(N / FBI, FNSPLIT);
        hipLaunchKernelGGL(fb_main, grid, dim3(256), 0, stream, emb, lab, ws, N);
        hipLaunchKernelGGL(fb_final, dim3(1), dim3(256), 0, stream, ws, out, N);
    }
}

// Round 14
// 47.913 us; speedup vs baseline: 2.1269x; 1.0145x over previous
//
#include <hip/hip_runtime.h>
#include <hip/hip_bf16.h>
#include <math.h>

#define N_D 128
#define TEMP_INV 14.285714285714286f
#define EXP2_SCALE 20.60992915555662f   // (1/0.07) * log2(e)
#define SQRT_E2S 4.539816f              // sqrt(EXP2_SCALE); folded into bf16 data

using bf16x8 = __attribute__((ext_vector_type(8))) short;
using f32x4  = __attribute__((ext_vector_type(4))) float;

// ---------------- ws layout (bytes), N=8192 fast path ----------------
#define EBF_OFF   0u          // 8192*128 bf16, PRE-SWIZZLED rows, PRE-SCALED by SQRT_E2S (2 MB)
#define SE_OFF    2097152u    // 8192 f32 row exp-sums (zeroed by k_pre misc block)
#define S_OFF     2129920u    // 100*128 f32 class sums (raw emb)
#define CNT_OFF   2181120u    // 100 f32 class counts
#define CTR_OFF   2181632u    // 256 ints: [0]=flag64 [1]=FIN(f32) [2]=DONE
#define WS_NEEDED 2182656u

__device__ __forceinline__ ushort f2bf(float f) {
    __hip_bfloat16 h = __float2bfloat16(f);
    return *reinterpret_cast<ushort*>(&h);
}

__device__ __forceinline__ float fast_exp2(float x) {
#if __has_builtin(__builtin_amdgcn_exp2f)
    return __builtin_amdgcn_exp2f(x);
#else
    float r; asm("v_exp_f32 %0, %1" : "=v"(r) : "v"(x)); return r;
#endif
}

__device__ __forceinline__ void glds16(const void* src, void* dst) {
    __builtin_amdgcn_global_load_lds(
        (const __attribute__((address_space(1))) unsigned int*)src,
        (__attribute__((address_space(3))) unsigned int*)dst, 16, 0, 0);
}

__device__ int detect_i64(const int* lab, int N) {
    __shared__ int s_any;
    if (threadIdx.x == 0) s_any = 0;
    __syncthreads();
    int any = 0;
    for (int i = threadIdx.x; i < (N >> 1); i += blockDim.x)
        any |= (lab[2 * i + 1] != 0);
    if (__any(any) && (threadIdx.x & 63) == 0) atomicOr(&s_any, 1);
    __syncthreads();
    return s_any ? 0 : 1;   // all odd words zero => int64
}

// ====== k_pre: [0,512) bf16 convert (pre-swizzled, pre-scaled) | [512,612) class sums | 612 misc ======
__global__ __launch_bounds__(256) void k_pre(const float* __restrict__ emb,
                                             const int* __restrict__ lab,
                                             char* __restrict__ ws, int N) {
    __shared__ int list[1024];
    __shared__ int lcnt;
    __shared__ float tmp[128];
    const int blk = blockIdx.x;
    const int tid = threadIdx.x;

    if (blk < 512) {
        // convert: id -> row g, slot s; store orig[g][s ^ (g&15)] at [g][s], scaled
        int id = blk * 256 + tid;            // 0 .. 131071
        int g = id >> 4, s = id & 15;
        int srcslot = s ^ (g & 15);
        const float* src = emb + (size_t)g * N_D + srcslot * 8;
        float4 v0 = *(const float4*)src;
        float4 v1 = *(const float4*)(src + 4);
        uint4 o;
        o.x = (uint)f2bf(v0.x * SQRT_E2S) | ((uint)f2bf(v0.y * SQRT_E2S) << 16);
        o.y = (uint)f2bf(v0.z * SQRT_E2S) | ((uint)f2bf(v0.w * SQRT_E2S) << 16);
        o.z = (uint)f2bf(v1.x * SQRT_E2S) | ((uint)f2bf(v1.y * SQRT_E2S) << 16);
        o.w = (uint)f2bf(v1.z * SQRT_E2S) | ((uint)f2bf(v1.w * SQRT_E2S) << 16);
        ((uint4*)(ws + EBF_OFF))[id] = o;
        return;
    }
    if (blk < 612) {
        // class-sum for class c: one full-N index list, then 8-deep ILP row sums
        int c = blk - 512;
        int flag64 = detect_i64(lab, N);
        if (tid == 0) lcnt = 0;
        __syncthreads();
        for (int i = tid; i < N; i += 256) {
            int L = flag64 ? lab[2 * i] : lab[i];
            if (L == c) list[atomicAdd(&lcnt, 1) & 1023] = i;
        }
        __syncthreads();
        int n = lcnt; if (n > 1024) n = 1024;
        int stream = tid >> 7;      // 0/1
        int d = tid & 127;
        float acc = 0.f;
        int j = stream;
        while (j + 14 < n) {        // 8 independent loads in flight
            float t0 = emb[(size_t)list[j     ] * N_D + d];
            float t1 = emb[(size_t)list[j +  2] * N_D + d];
            float t2 = emb[(size_t)list[j +  4] * N_D + d];
            float t3 = emb[(size_t)list[j +  6] * N_D + d];
            float t4 = emb[(size_t)list[j +  8] * N_D + d];
            float t5 = emb[(size_t)list[j + 10] * N_D + d];
            float t6 = emb[(size_t)list[j + 12] * N_D + d];
            float t7 = emb[(size_t)list[j + 14] * N_D + d];
            acc += ((t0 + t1) + (t2 + t3)) + ((t4 + t5) + (t6 + t7));
            j += 16;
        }
        for (; j < n; j += 2) acc += emb[(size_t)list[j] * N_D + d];
        if (stream == 1) tmp[d] = acc;
        __syncthreads();
        if (stream == 0) {
            ((float*)(ws + S_OFF))[c * N_D + d] = acc + tmp[d];
            if (d == 0) ((float*)(ws + CNT_OFF))[c] = (float)n;
        }
        return;
    }
    // misc block: flag + zero se + zero all counters
    {
        int flag64 = detect_i64(lab, N);
        float* se = (float*)(ws + SE_OFF);
        for (int i = tid; i < N; i += 256) se[i] = 0.f;
        int* ctrs = (int*)(ws + CTR_OFF);
        if (tid < 256) ctrs[tid] = (tid == 0) ? flag64 : 0;
    }
}

// ====== k_main: BJ=128, 512 blocks, (256,2); counted-vmcnt + phase-split epilogue + setprio ======
__global__ __launch_bounds__(256, 2) void k_main(char* __restrict__ ws, int N) {
    __shared__ __attribute__((aligned(128))) char smem[65536];  // buf0/buf1 32KB each

    const char* ebf = ws + EBF_OFF;
    float* se_ws = (float*)(ws + SE_OFF);

    const int bid = blockIdx.x;            // 512 = 64 rowblocks x 8 splits
    const int rowblk = bid & 63;           // bid%8 = rowblk%8 -> rowblock pinned to one XCD
    const int s8 = bid >> 6;               // 0..7
    const int rowbase = rowblk * 128;
    const int t0 = s8 * 8;                 // 128-col tile range [t0, t0+8)
    const int t1 = t0 + 8;

    const int tid = threadIdx.x;
    const int lane = tid & 63;
    const int wave = tid >> 6;
    const int wr = wave >> 1, wc = wave & 1;   // 2x2: 64 rows x 64 cols per wave
    const int l15 = lane & 15, lhi = lane >> 4;

    // ---- stage A (128 x 256B = 32 KB) into buf0 ----
    {
        const char* src = ebf + ((size_t)(rowbase + wave * 32 + lhi) << 8) + (l15 << 4);
        char* dst = smem + wave * 8192;
        #pragma unroll
        for (int i = 0; i < 8; ++i) glds16(src + i * 1024, dst + i * 1024);
    }
    __syncthreads();
    // ---- hoist A fragments to registers ----
    bf16x8 aF[4][4];   // [rf][ks] = 64 VGPRs
    #pragma unroll
    for (int rf = 0; rf < 4; ++rf) {
        int row = wr * 64 + rf * 16 + l15;
        #pragma unroll
        for (int ks = 0; ks < 4; ++ks)
            aF[rf][ks] = *(const bf16x8*)(smem + row * 256 + ((ks * 64 + lhi * 16) ^ (l15 << 4)));
    }
    __syncthreads();   // hoists done, buf0 free

    // ---- prologue: issue B(t0) stage into buf0, NO wait (loop will count it) ----
    {
        const char* src = ebf + ((size_t)(t0 * 128 + wave * 32 + lhi) << 8) + (l15 << 4);
        char* dst = smem + wave * 8192;
        #pragma unroll
        for (int i = 0; i < 8; ++i) glds16(src + i * 1024, dst + i * 1024);
    }

    float se[4][4];
    #pragma unroll
    for (int rf = 0; rf < 4; ++rf)
        #pragma unroll
        for (int reg = 0; reg < 4; ++reg) se[rf][reg] = 0.f;

    int pb = 0;
    for (int t = t0; t < t1; ++t) {
        // barrier 1: all waves done computing t-1 -> buf[pb^1] is reusable
        __builtin_amdgcn_s_barrier();
        if (t + 1 < t1) {
            // stage next tile into the freed buffer; keep its loads IN FLIGHT
            const char* src = ebf + ((size_t)((t + 1) * 128 + wave * 32 + lhi) << 8) + (l15 << 4);
            char* dst = smem + (pb ^ 1) * 32768 + wave * 8192;
            #pragma unroll
            for (int i = 0; i < 8; ++i) glds16(src + i * 1024, dst + i * 1024);
            asm volatile("s_waitcnt vmcnt(8)" ::: "memory");   // only B(t)'s 8 must land
        } else {
            asm volatile("s_waitcnt vmcnt(0)" ::: "memory");
        }
        // barrier 2: every wave's B(t) loads landed -> tile visible to all
        __builtin_amdgcn_s_barrier();

        const char* cur = smem + pb * 32768;
        unsigned dgu = (unsigned)(t * 128 - rowbase);
        bool hd = (dgu == 0u);

        f32x4 acc[4][4];
        #pragma unroll
        for (int rf = 0; rf < 4; ++rf)
            #pragma unroll
            for (int cf = 0; cf < 4; ++cf) acc[rf][cf] = (f32x4){0.f, 0.f, 0.f, 0.f};

        // ---- phase 1: MFMAs for cf 0,1 ----
        __builtin_amdgcn_s_setprio(1);
        #pragma unroll
        for (int ks = 0; ks < 4; ++ks) {
            const int kb = (ks * 64 + lhi * 16) ^ (l15 << 4);
            bf16x8 bF[2];
            #pragma unroll
            for (int cf = 0; cf < 2; ++cf)
                bF[cf] = *(const bf16x8*)(cur + (wc * 64 + cf * 16 + l15) * 256 + kb);
            #pragma unroll
            for (int rf = 0; rf < 4; ++rf)
                #pragma unroll
                for (int cf = 0; cf < 2; ++cf)
                    acc[rf][cf] = __builtin_amdgcn_mfma_f32_16x16x32_bf16(
                        aF[rf][ks], bF[cf], acc[rf][cf], 0, 0, 0);
        }
        __builtin_amdgcn_s_setprio(0);

#define EPI_CF(cf)                                                            \
        _Pragma("unroll")                                                     \
        for (int rf = 0; rf < 4; ++rf)                                        \
            _Pragma("unroll")                                                 \
            for (int reg = 0; reg < 4; ++reg) {                               \
                float e = fast_exp2(acc[rf][cf][reg]);                        \
                if (hd) {                                                     \
                    int lrow = wr * 64 + rf * 16 + lhi * 4 + reg;             \
                    int lcol = wc * 64 + (cf) * 16 + l15;                     \
                    e = (lrow == lcol) ? 0.f : e;                             \
                }                                                             \
                se[rf][reg] += e;                                             \
            }

        // ---- phase 2: MFMAs for cf 2,3 — epilogue of cf 0,1 is independent,
        //      so the trans-pipe ops fill the matrix-pipe shadow ----
        __builtin_amdgcn_s_setprio(1);
        #pragma unroll
        for (int ks = 0; ks < 4; ++ks) {
            const int kb = (ks * 64 + lhi * 16) ^ (l15 << 4);
            bf16x8 bF[2];
            #pragma unroll
            for (int cf = 0; cf < 2; ++cf)
                bF[cf] = *(const bf16x8*)(cur + (wc * 64 + (cf + 2) * 16 + l15) * 256 + kb);
            #pragma unroll
            for (int rf = 0; rf < 4; ++rf)
                #pragma unroll
                for (int cf = 0; cf < 2; ++cf)
                    acc[rf][cf + 2] = __builtin_amdgcn_mfma_f32_16x16x32_bf16(
                        aF[rf][ks], bF[cf], acc[rf][cf + 2], 0, 0, 0);
        }
        __builtin_amdgcn_s_setprio(0);
        EPI_CF(0)
        EPI_CF(1)
        EPI_CF(2)
        EPI_CF(3)
#undef EPI_CF

        pb ^= 1;
    }

    // ---- reduce over 16 col-lanes, one atomic per row ----
    #pragma unroll
    for (int m = 1; m < 16; m <<= 1)
        #pragma unroll
        for (int rf = 0; rf < 4; ++rf)
            #pragma unroll
            for (int reg = 0; reg < 4; ++reg)
                se[rf][reg] += __shfl_xor(se[rf][reg], m);
    if (l15 == 0) {
        #pragma unroll
        for (int rf = 0; rf < 4; ++rf)
            #pragma unroll
            for (int reg = 0; reg < 4; ++reg) {
                int row = rowbase + wr * 64 + rf * 16 + lhi * 4 + reg;
                atomicAdd(&se_ws[row], se[rf][reg]);
            }
    }
}

// ============ k_rowfinal: per-row analytic pos-sum + combine + write out ============
__global__ __launch_bounds__(256) void k_rowfinal(const float* __restrict__ emb,
                                                  const int* __restrict__ lab,
                                                  char* __restrict__ ws,
                                                  float* __restrict__ out, int N) {
    __shared__ float red[256];
    int* ctrs = (int*)(ws + CTR_OFF);
    const int r = blockIdx.x * 256 + threadIdx.x;
    const int flag64 = ctrs[0];
    float contrib = 0.f;
    if (r < N) {
        int L = flag64 ? lab[2 * r] : lab[r];
        const float* Sr = (const float*)(ws + S_OFF) + L * N_D;
        const float* er = emb + (size_t)r * N_D;
        float dot = 0.f, nrm = 0.f;
        #pragma unroll 8
        for (int k = 0; k < N_D; k += 4) {
            float4 e = *(const float4*)(er + k);
            float4 s4 = *(const float4*)(Sr + k);
            dot += e.x * s4.x + e.y * s4.y + e.z * s4.z + e.w * s4.w;
            nrm += e.x * e.x + e.y * e.y + e.z * e.z + e.w * e.w;
        }
        float pc = ((const float*)(ws + CNT_OFF))[L] - 1.f;
        float sev = ((const float*)(ws + SE_OFF))[r];
        if (pc > 0.f)
            contrib = ((dot - nrm) * TEMP_INV - pc * __logf(sev + 1e-9f)) / pc;
    }
    red[threadIdx.x] = contrib;
    __syncthreads();
    for (int s = 128; s > 0; s >>= 1) {
        if (threadIdx.x < s) red[threadIdx.x] += red[threadIdx.x + s];
        __syncthreads();
    }
    if (threadIdx.x == 0) {
        atomicAdd((float*)&ctrs[1], red[0]);
        __threadfence();
        if (atomicAdd(&ctrs[2], 1) == (int)gridDim.x - 1) {
            float fin = atomicAdd((float*)&ctrs[1], 0.0f);   // device-scope read
            out[0] = -fin / (float)N;
        }
    }
}

// ======================= fallback (round-2 proven path) =======================
#define FBI 128
#define FBJ 64
#define FNSPLIT 8

__global__ void fb_prep(const int* __restrict__ lab32, float* __restrict__ ws, int N) {
    int tid = blockIdx.x * blockDim.x + threadIdx.x;
    int total = 3 * N;
    for (int i = tid; i < total; i += gridDim.x * blockDim.x) ws[i] = 0.0f;
    if (blockIdx.x == 0) {
        __shared__ int nz;
        if (threadIdx.x == 0) nz = 0;
        __syncthreads();
        int local = 0;
        int half = N >> 1;
        for (int i = threadIdx.x; i < half; i += blockDim.x)
            if (lab32[2 * i + 1] != 0) local = 1;
        if (local) atomicOr(&nz, 1);
        __syncthreads();
        if (threadIdx.x == 0) ((int*)ws)[3 * N] = (nz == 0) ? 1 : 0;
    }
}

__global__ __launch_bounds__(256) void fb_main(const float* __restrict__ emb,
                                               const int* __restrict__ lab32,
                                               float* __restrict__ ws, int N) {
    __shared__ ushort Ash[FBI * N_D];
    __shared__ ushort Bsh[FBJ * N_D];
    __shared__ int labA[FBI];
    __shared__ int labB[FBJ];

    const int tid  = threadIdx.x;
    const int lane = tid & 63;
    const int wave = tid >> 6;
    const int wr = wave >> 1;
    const int wc = wave & 1;
    const int l15 = lane & 15;
    const int lhi = lane >> 4;
    const int rowbase  = blockIdx.x * FBI;
    const int colsPer  = N / FNSPLIT;
    const int colstart = blockIdx.y * colsPer;
    const int flag64 = ((const int*)ws)[3 * N];

    for (int id = tid; id < FBI * 32; id += 256) {
        int row = id >> 5, k4 = id & 31;
        float4 v = *(const float4*)&emb[(size_t)(rowbase + row) * N_D + (k4 << 2)];
        uint p0 = (uint)f2bf(v.x) | ((uint)f2bf(v.y) << 16);
        uint p1 = (uint)f2bf(v.z) | ((uint)f2bf(v.w) << 16);
        int byte = (row << 8) + (k4 << 3);
        byte ^= (row & 7) << 4;
        *(uint2*)((char*)Ash + byte) = make_uint2(p0, p1);
    }
    if (tid < FBI) {
        int g = rowbase + tid;
        labA[tid] = flag64 ? lab32[2 * g] : lab32[g];
    }
    __syncthreads();

    int labR[4][4];
    const int rowc = rowbase + wr * 64 + lhi * 4;
    #pragma unroll
    for (int rf = 0; rf < 4; ++rf)
        #pragma unroll
        for (int reg = 0; reg < 4; ++reg)
            labR[rf][reg] = labA[wr * 64 + rf * 16 + lhi * 4 + reg];

    float se[4][4], ps[4][4], pc[4][4];
    #pragma unroll
    for (int rf = 0; rf < 4; ++rf)
        #pragma unroll
        for (int reg = 0; reg < 4; ++reg) { se[rf][reg] = 0.f; ps[rf][reg] = 0.f; pc[rf][reg] = 0.f; }

    for (int jt = colstart; jt < colstart + colsPer; jt += FBJ) {
        __syncthreads();
        for (int id = tid; id < FBJ * 32; id += 256) {
            int row = id >> 5, k4 = id & 31;
            float4 v = *(const float4*)&emb[(size_t)(jt + row) * N_D + (k4 << 2)];
            uint p0 = (uint)f2bf(v.x) | ((uint)f2bf(v.y) << 16);
            uint p1 = (uint)f2bf(v.z) | ((uint)f2bf(v.w) << 16);
            int byte = (row << 8) + (k4 << 3);
            byte ^= (row & 7) << 4;
            *(uint2*)((char*)Bsh + byte) = make_uint2(p0, p1);
        }
        if (tid < FBJ) {
            int g = jt + tid;
            labB[tid] = flag64 ? lab32[2 * g] : lab32[g];
        }
        __syncthreads();

        f32x4 zero4 = {0.f, 0.f, 0.f, 0.f};
        f32x4 acc[4][2];
        #pragma unroll
        for (int rf = 0; rf < 4; ++rf)
            #pragma unroll
            for (int cf = 0; cf < 2; ++cf) acc[rf][cf] = zero4;

        const int kbyteBase = lhi * 16;
        #pragma unroll
        for (int ks = 0; ks < 4; ++ks) {
            int kb = ks * 64 + kbyteBase;
            bf16x8 aF[4], bF[2];
            #pragma unroll
            for (int rf = 0; rf < 4; ++rf) {
                int row = wr * 64 + rf * 16 + l15;
                int byte = (row << 8) + kb;
                byte ^= (row & 7) << 4;
                aF[rf] = *(bf16x8*)((char*)Ash + byte);
            }
            #pragma unroll
            for (int cf = 0; cf < 2; ++cf) {
                int col = wc * 32 + cf * 16 + l15;
                int byte = (col << 8) + kb;
                byte ^= (col & 7) << 4;
                bF[cf] = *(bf16x8*)((char*)Bsh + byte);
            }
            #pragma unroll
            for (int rf = 0; rf < 4; ++rf)
                #pragma unroll
                for (int cf = 0; cf < 2; ++cf)
                    acc[rf][cf] = __builtin_amdgcn_mfma_f32_16x16x32_bf16(
                        aF[rf], bF[cf], acc[rf][cf], 0, 0, 0);
        }

        int labC[2], gcol[2];
        #pragma unroll
        for (int cf = 0; cf < 2; ++cf) {
            int col = wc * 32 + cf * 16 + l15;
            labC[cf] = labB[col];
            gcol[cf] = jt + col;
        }
        bool hasdiag = (jt < rowbase + FBI) && (jt + FBJ > rowbase);

#define EPILOGUE(HD)                                                          \
        _Pragma("unroll")                                                     \
        for (int cf = 0; cf < 2; ++cf) {                                      \
            _Pragma("unroll")                                                 \
            for (int rf = 0; rf < 4; ++rf) {                                  \
                _Pragma("unroll")                                             \
                for (int reg = 0; reg < 4; ++reg) {                           \
                    float sim = acc[rf][cf][reg] * TEMP_INV;                  \
                    float e = __expf(sim);                                    \
                    bool pos = (labR[rf][reg] == labC[cf]);                   \
                    if (HD) {                                                 \
                        bool diag = ((rowc + rf * 16 + reg) == gcol[cf]);     \
                        e = diag ? 0.f : e;                                   \
                        pos = pos && !diag;                                   \
                    }                                                         \
                    se[rf][reg] += e;                                         \
                    ps[rf][reg] += pos ? sim : 0.f;                           \
                    pc[rf][reg] += pos ? 1.f : 0.f;                           \
                }                                                             \
            }                                                                 \
        }

        if (hasdiag) { EPILOGUE(true) } else { EPILOGUE(false) }
#undef EPILOGUE
    }

    for (int m = 1; m < 16; m <<= 1) {
        #pragma unroll
        for (int rf = 0; rf < 4; ++rf)
            #pragma unroll
            for (int reg = 0; reg < 4; ++reg) {
                se[rf][reg] += __shfl_xor(se[rf][reg], m);
                ps[rf][reg] += __shfl_xor(ps[rf][reg], m);
                pc[rf][reg] += __shfl_xor(pc[rf][reg], m);
            }
    }
    if (l15 == 0) {
        #pragma unroll
        for (int rf = 0; rf < 4; ++rf)
            #pragma unroll
            for (int reg = 0; reg < 4; ++reg) {
                int row = rowc + rf * 16 + reg;
                atomicAdd(&ws[row],         se[rf][reg]);
                atomicAdd(&ws[N + row],     ps[rf][reg]);
                atomicAdd(&ws[2 * N + row], pc[rf][reg]);
            }
    }
}

__global__ void fb_final(const float* __restrict__ ws, float* __restrict__ out, int N) {
    __shared__ float red[256];
    float local = 0.0f;
    for (int i = threadIdx.x; i < N; i += 256) {
        float sev = ws[i], psv = ws[N + i], pcv = ws[2 * N + i];
        float lp = psv - pcv * logf(sev + 1e-9f);
        float denom = (pcv == 0.0f) ? 1.0f : pcv;
        local += lp / denom;
    }
    red[threadIdx.x] = local;
    __syncthreads();
    for (int s = 128; s > 0; s >>= 1) {
        if (threadIdx.x < s) red[threadIdx.x] += red[threadIdx.x + s];
        __syncthreads();
    }
    if (threadIdx.x == 0) out[0] = -red[0] / (float)N;
}

// ======================= launcher =======================
extern "C" void kernel_launch(void* const* d_in, const int* in_sizes, int n_in,
                              void* d_out, int out_size, void* d_ws, size_t ws_size,
                              hipStream_t stream) {
    const float* emb = (const float*)d_in[0];
    const int* lab = (const int*)d_in[1];
    float* out = (float*)d_out;
    const int N = in_sizes[0] / N_D;

    if (N == 8192 && ws_size >= (size_t)WS_NEEDED) {
        char* ws = (char*)d_ws;
        hipLaunchKernelGGL(k_pre, dim3(613), dim3(256), 0, stream, emb, lab, ws, N);
        hipLaunchKernelGGL(k_main, dim3(512), dim3(256), 0, stream, ws, N);
        hipLaunchKernelGGL(k_rowfinal, dim3(32), dim3(256), 0, stream, emb, lab, ws, out, N);
    } else {
        float* ws = (float*)d_ws;
        hipLaunchKernelGGL(fb_prep, dim3(32), dim3(256), 0, stream, lab, ws, N);
        dim3 grid(N / FBI, FNSPLIT);
        hipLaunchKernelGGL(fb_main, grid, dim3(256), 0, stream, emb, lab, ws, N);
        hipLaunchKernelGGL(fb_final, dim3(1), dim3(256), 0, stream, ws, out, N);
    }
}